// Round 1
// baseline (200.908 us; speedup 1.0000x reference)
//
#include <hip/hip_runtime.h>
#include <hip/hip_bf16.h>

#define B_ 8
#define S1_ 2048
#define S2_ 2048
#define D_ 512
#define F_ 256

typedef __attribute__((ext_vector_type(4))) float f32x4;
typedef __attribute__((ext_vector_type(8))) short s16x8;
typedef __attribute__((ext_vector_type(4))) short s16x4;

__device__ __forceinline__ short f2bf(float x) {
  union { float f; unsigned u; } v; v.f = x;
  unsigned r = v.u + 0x7fffu + ((v.u >> 16) & 1u);
  return (short)(r >> 16);
}

__device__ __forceinline__ int pk2bf(float a, float b) {
  union { __hip_bfloat162 h; int i; } u;
  u.h = __float22bfloat162_rn(make_float2(a, b));
  return u.i;
}

// async global->LDS, 16B per lane, LDS dest = wave-uniform base + lane*16
__device__ __forceinline__ void gll16(const short* g, short* l) {
  __builtin_amdgcn_global_load_lds(
      (const __attribute__((address_space(1))) void*)g,
      (__attribute__((address_space(3))) void*)l, 16, 0, 0);
}

// ---------------- weight transpose via LDS tile (coalesced both ways) ------
__global__ __launch_bounds__(256) void wtrans_kernel(
    const float* __restrict__ Wq, const float* __restrict__ Wk,
    const float* __restrict__ Wv, const float* __restrict__ Wfc,
    short* __restrict__ Wqt, short* __restrict__ Wkt,
    short* __restrict__ Wvt, short* __restrict__ Wfct) {
  int y = blockIdx.y;
  const float* W; short* Wt; int D;
  if (y == 0)      { W = Wq;  Wt = Wqt;  D = 512; }
  else if (y == 1) { W = Wk;  Wt = Wkt;  D = 512; }
  else if (y == 2) { W = Wv;  Wt = Wvt;  D = 512; }
  else             { W = Wfc; Wt = Wfct; D = 256; }
  int tiles_d = D >> 6;
  int bx = blockIdx.x;
  if (bx >= tiles_d * 4) return;
  int d0 = (bx % tiles_d) * 64, f0 = (bx / tiles_d) * 64;

  __shared__ short Ts[64][68];
  int t = threadIdx.x;
  int r = t >> 2, c16 = (t & 3) * 16;
  {
    const float* src = W + (size_t)(d0 + r) * F_ + f0 + c16;
    f32x4 v0 = *(const f32x4*)(src);
    f32x4 v1 = *(const f32x4*)(src + 4);
    f32x4 v2 = *(const f32x4*)(src + 8);
    f32x4 v3 = *(const f32x4*)(src + 12);
    s16x8 s0, s1;
    ((int*)&s0)[0] = pk2bf(v0[0], v0[1]); ((int*)&s0)[1] = pk2bf(v0[2], v0[3]);
    ((int*)&s0)[2] = pk2bf(v1[0], v1[1]); ((int*)&s0)[3] = pk2bf(v1[2], v1[3]);
    ((int*)&s1)[0] = pk2bf(v2[0], v2[1]); ((int*)&s1)[1] = pk2bf(v2[2], v2[3]);
    ((int*)&s1)[2] = pk2bf(v3[0], v3[1]); ((int*)&s1)[3] = pk2bf(v3[2], v3[3]);
    *(s16x8*)(&Ts[r][c16]) = s0;
    *(s16x8*)(&Ts[r][c16 + 8]) = s1;
  }
  __syncthreads();
  {
    int fr = t >> 2, dc16 = (t & 3) * 16;
    s16x8 o0, o1;
    for (int j = 0; j < 8; ++j) o0[j] = Ts[dc16 + j][fr];
    for (int j = 0; j < 8; ++j) o1[j] = Ts[dc16 + 8 + j][fr];
    short* dst = Wt + (size_t)(f0 + fr) * D + d0 + dc16;
    *(s16x8*)dst = o0;
    *(s16x8*)(dst + 8) = o1;
  }
}

// ---------------- QKV projection: 64 rows x 256 cols (full N), BK=64 ------
// R5 version verbatim: 256 threads, 3 blocks/CU. Proven fastest proj combo.
__global__ __launch_bounds__(256, 3) void proj_kernel(
    const float* __restrict__ feat1, const float* __restrict__ feat2,
    const short* __restrict__ Wqt, const short* __restrict__ Wkt,
    const short* __restrict__ Wvt,
    const float* __restrict__ bq, const float* __restrict__ bk,
    const float* __restrict__ bv,
    short* __restrict__ Qw, short* __restrict__ Kw, short* __restrict__ Vtw) {
  const float* A; const short* Wt; const float* bias; short* outp;
  float scale; int trans;
  if (blockIdx.y == 0)      { A = feat1; Wt = Wqt; bias = bq; outp = Qw;  scale = 0.0625f; trans = 0; }
  else if (blockIdx.y == 1) { A = feat2; Wt = Wkt; bias = bk; outp = Kw;  scale = 1.0f;    trans = 0; }
  else                      { A = feat2; Wt = Wvt; bias = bv; outp = Vtw; scale = 1.0f;    trans = 1; }

  __shared__ __align__(16) short As[64][72];    // A tile 64x64 bf16
  __shared__ __align__(16) short Ws[256][72];   // W tile 256x64 bf16

  int m0 = blockIdx.x * 64;
  int t = threadIdx.x;
  int w = t >> 6, L = t & 63, rowA = L & 15, quad = L >> 4;
  int ar = t >> 2, ac16 = (t & 3) * 16;   // A staging: 4 lanes/row

  f32x4 acc[4][4];
  for (int i = 0; i < 4; ++i)
    for (int j = 0; j < 4; ++j) acc[i][j] = (f32x4){0.f, 0.f, 0.f, 0.f};

  for (int k0 = 0; k0 < D_; k0 += 64) {
    {   // stage A 64x64 fp32->bf16: each thread 16 floats
      const float* src = A + (size_t)(m0 + ar) * D_ + k0 + ac16;
      f32x4 v0 = *(const f32x4*)(src);
      f32x4 v1 = *(const f32x4*)(src + 4);
      f32x4 v2 = *(const f32x4*)(src + 8);
      f32x4 v3 = *(const f32x4*)(src + 12);
      s16x8 s0, s1;
      ((int*)&s0)[0] = pk2bf(v0[0], v0[1]); ((int*)&s0)[1] = pk2bf(v0[2], v0[3]);
      ((int*)&s0)[2] = pk2bf(v1[0], v1[1]); ((int*)&s0)[3] = pk2bf(v1[2], v1[3]);
      ((int*)&s1)[0] = pk2bf(v2[0], v2[1]); ((int*)&s1)[1] = pk2bf(v2[2], v2[3]);
      ((int*)&s1)[2] = pk2bf(v3[0], v3[1]); ((int*)&s1)[3] = pk2bf(v3[2], v3[3]);
      *(s16x8*)(&As[ar][ac16]) = s0;
      *(s16x8*)(&As[ar][ac16 + 8]) = s1;
    }
    for (int p = 0; p < 4; ++p) {   // stage W 256x64: 4 passes of 64 rows
      int r = (t >> 2) + p * 64;
      const short* src = Wt + (size_t)r * D_ + k0 + ac16;
      *(s16x8*)(&Ws[r][ac16]) = *(const s16x8*)(src);
      *(s16x8*)(&Ws[r][ac16 + 8]) = *(const s16x8*)(src + 8);
    }
    __syncthreads();
    for (int kt = 0; kt < 2; ++kt) {
      s16x8 a[4];
      for (int mt = 0; mt < 4; ++mt)
        a[mt] = *(const s16x8*)(&As[mt * 16 + rowA][kt * 32 + quad * 8]);
      for (int nt = 0; nt < 4; ++nt) {
        s16x8 bfr = *(const s16x8*)(&Ws[w * 64 + nt * 16 + rowA][kt * 32 + quad * 8]);
        for (int mt = 0; mt < 4; ++mt)
          acc[mt][nt] = __builtin_amdgcn_mfma_f32_16x16x32_bf16(a[mt], bfr, acc[mt][nt], 0, 0, 0);
      }
    }
    __syncthreads();
  }

  if (!trans) {
    float bn[4];
    for (int nt = 0; nt < 4; ++nt) bn[nt] = bias[w * 64 + nt * 16 + rowA];
    for (int mt = 0; mt < 4; ++mt) {
      int m = m0 + mt * 16 + quad * 4;
      for (int nt = 0; nt < 4; ++nt) {
        int n = w * 64 + nt * 16 + rowA;
        for (int r = 0; r < 4; ++r)
          outp[(size_t)(m + r) * F_ + n] = f2bf((acc[mt][nt][r] + bn[nt]) * scale);
      }
    }
  } else {
    int bb = m0 >> 11;
    int tbase = m0 & (S2_ - 1);
    float bn[4];
    for (int nt = 0; nt < 4; ++nt) bn[nt] = bias[w * 64 + nt * 16 + rowA];
    for (int nt = 0; nt < 4; ++nt) {
      int f = w * 64 + nt * 16 + rowA;
      for (int mt = 0; mt < 4; ++mt) {
        int tt = tbase + mt * 16 + quad * 4;
        s16x4 o;
        for (int r = 0; r < 4; ++r) o[r] = f2bf(acc[mt][nt][r] + bn[nt]);
        *(s16x4*)(outp + ((size_t)bb * F_ + f) * S2_ + tt) = o;
      }
    }
  }
}

// ---------------- flash attention + fused FC epilogue ---------------------
// Changes vs R8: (1) K/V staged via global_load_lds (no ds_write, no VGPR
// prefetch), linear LDS rows + XOR chunk swizzle (chunk ^= row&7) applied on
// the inverse at the GLOBAL source and on every ds_read; (2) PV waves retiled
// 32x128 -> 64x64 (16 LDS reads/iter instead of 20); (3) FC GEMM fused as an
// epilogue: normalized O -> LDS (reusing dead K buffers), all 8 waves GEMM
// against L2-resident Wfct, write fp32 out directly. fc_kernel removed.
__global__ __launch_bounds__(512, 2) void flash_kernel(
    const short* __restrict__ Q,    // [B][S1][F] bf16 (scaled)
    const short* __restrict__ K,    // [B][S2][F] bf16
    const short* __restrict__ Vt,   // [B][F][S2] bf16
    const short* __restrict__ Wfct, // [F g][F k] bf16
    const float* __restrict__ bfc,
    float* __restrict__ out) {      // [B][S1][F] fp32
  __shared__ __align__(16) short Ks[2][64][256];   // 65536 B, swizzled rows
  __shared__ __align__(16) short Vs[2][256][64];   // 65536 B, swizzled rows
  __shared__ __align__(16) short Ps[2][64][72];    // 18432 B
  __shared__ float lf[128];                        // 512 B  (total 150016)

  int b = blockIdx.x & 7;            // XCD-aware: batch = block % 8
  int s0 = (blockIdx.x >> 3) * 64;
  int t = threadIdx.x;
  int w = t >> 6, L = t & 63, rowA = L & 15, quad = L >> 4;
  int isS = (w < 4);

  const short* Kb = K + (size_t)b * S2_ * F_;
  const short* Vb = Vt + (size_t)b * F_ * S2_;

  int rs = (w & 1) * 32, cs = ((w >> 1) & 1) * 32;   // S-wave quadrant
  int kxor = (rowA & 7) << 4;        // read-side XOR (row&7 == rowA&7)

  // Q fragments in registers (S-waves only)
  s16x8 qf[2][8];
  if (isS) {
    const short* Qb = Q + ((size_t)b * S1_ + s0 + rs) * F_;
    for (int mt = 0; mt < 2; ++mt)
      for (int kt = 0; kt < 8; ++kt)
        qf[mt][kt] = *(const s16x8*)(Qb + (size_t)(mt * 16 + rowA) * F_ + kt * 32 + quad * 8);
  }
  f32x4 o[4][4];
  for (int i = 0; i < 4; ++i)
    for (int j = 0; j < 4; ++j) o[i][j] = (f32x4){0.f, 0.f, 0.f, 0.f};
  float l_lane[2][4] = {{0.f,0.f,0.f,0.f},{0.f,0.f,0.f,0.f}};

  // prologue: K tile 0 -> Ks[0] (source pre-swizzled, LDS dest linear)
  {
    int vL5 = L >> 5, vc = L & 31;
#pragma unroll
    for (int j = 0; j < 4; ++j) {
      int row = 8 * w + 2 * j + vL5;
      const short* src = Kb + (size_t)row * F_ + ((vc ^ (row & 7)) << 3);
      gll16(src, &Ks[0][8 * w + 2 * j][0]);
    }
  }

  for (int it = 0; it <= 32; ++it) {
    int cb = it & 1;
    __syncthreads();   // drains vmcnt -> all gll issued last iter have landed
    if (it < 32) {
      // V tile it -> Vs[cb] (consumed next iter)
      int vn0 = it << 6;
      int vL3 = L >> 3, vxor = ((L & 7) ^ ((L >> 3) & 7)) << 3;
#pragma unroll
      for (int j = 0; j < 4; ++j) {
        int row = 32 * w + 8 * j + vL3;
        const short* src = Vb + (size_t)row * S2_ + vn0 + vxor;
        gll16(src, &Vs[cb][32 * w + 8 * j][0]);
      }
      if (it < 31) {
        // K tile it+1 -> Ks[1-cb]
        int kn0 = (it + 1) << 6;
        int kL5 = L >> 5, kc = L & 31;
#pragma unroll
        for (int j = 0; j < 4; ++j) {
          int row = 8 * w + 2 * j + kL5;
          const short* src = Kb + (size_t)(kn0 + row) * F_ + ((kc ^ (row & 7)) << 3);
          gll16(src, &Ks[1 - cb][8 * w + 2 * j][0]);
        }
      }
    }
    if (isS) {
      if (it < 32) {
        f32x4 s[2][2];
        for (int i = 0; i < 2; ++i)
          for (int j = 0; j < 2; ++j) s[i][j] = (f32x4){0.f, 0.f, 0.f, 0.f};
        const char* kb0 = (const char*)&Ks[cb][0][0] + ((size_t)(cs + rowA) << 9);
        const char* kb1 = kb0 + (16 << 9);
#pragma unroll
        for (int kt = 0; kt < 8; ++kt) {
          int off = (kt * 64 + quad * 16) ^ kxor;
          s16x8 bf0 = *(const s16x8*)(kb0 + off);
          s16x8 bf1 = *(const s16x8*)(kb1 + off);
          for (int mt = 0; mt < 2; ++mt) {
            s[mt][0] = __builtin_amdgcn_mfma_f32_16x16x32_bf16(qf[mt][kt], bf0, s[mt][0], 0, 0, 0);
            s[mt][1] = __builtin_amdgcn_mfma_f32_16x16x32_bf16(qf[mt][kt], bf1, s[mt][1], 0, 0, 0);
          }
        }
        for (int mt = 0; mt < 2; ++mt)
          for (int nt = 0; nt < 2; ++nt)
            for (int r = 0; r < 4; ++r) {
              float p = __expf(s[mt][nt][r]);
              l_lane[mt][r] += p;
              Ps[cb][rs + mt * 16 + quad * 4 + r][cs + nt * 16 + rowA] = f2bf(p);
            }
      }
    } else {
      if (it > 0) {
        int pb = 1 - cb;
        s16x8 pa[4][2];
#pragma unroll
        for (int mt = 0; mt < 4; ++mt)
          for (int kt = 0; kt < 2; ++kt)
            pa[mt][kt] = *(const s16x8*)(&Ps[pb][mt * 16 + rowA][kt * 32 + quad * 8]);
        const char* vb0 = (const char*)&Vs[pb][0][0] + (size_t)((w - 4) * 64 + rowA) * 128;
#pragma unroll
        for (int ft = 0; ft < 4; ++ft)
          for (int kt = 0; kt < 2; ++kt) {
            int off = (kt * 64 + quad * 16) ^ kxor;
            s16x8 vf = *(const s16x8*)(vb0 + (size_t)(ft * 16) * 128 + off);
            for (int mt = 0; mt < 4; ++mt)
              o[mt][ft] = __builtin_amdgcn_mfma_f32_16x16x32_bf16(pa[mt][kt], vf, o[mt][ft], 0, 0, 0);
          }
      }
    }
  }

  // ---- row-sum reduction (S-waves) ----
  if (isS) {
    for (int mt = 0; mt < 2; ++mt)
      for (int r = 0; r < 4; ++r) {
        float x = l_lane[mt][r];
        for (int off = 1; off < 16; off <<= 1)
          x += __shfl_xor(x, off, 64);
        if (rowA == 0)
          lf[((w >> 1) & 1) * 64 + rs + mt * 16 + quad * 4 + r] = x;
      }
  }
  __syncthreads();

  // ---- normalized O (bf16) -> LDS, reusing dead K buffers ----
  short (*Olds)[264] = (short (*)[264])(&Ks[0][0][0]);   // 64x264 = 33792 B
  if (!isS) {
    int fgc = (w - 4) * 64;
    for (int mt = 0; mt < 4; ++mt)
      for (int r = 0; r < 4; ++r) {
        int row = mt * 16 + quad * 4 + r;
        float inv = 1.0f / (lf[row] + lf[64 + row]);
        for (int ft = 0; ft < 4; ++ft)
          Olds[row][fgc + ft * 16 + rowA] = f2bf(o[mt][ft][r] * inv);
      }
  }
  __syncthreads();

  // ---- fused FC: all 8 waves, out[64][256] = Olds[64x256] @ Wfc + bfc ----
  int mrow = (w & 3) * 16;       // 4 M-groups x 2 N-groups
  int ng = (w >> 2) * 128;
  f32x4 fc[8];
  for (int i = 0; i < 8; ++i) fc[i] = (f32x4){0.f, 0.f, 0.f, 0.f};
#pragma unroll
  for (int kt = 0; kt < 8; ++kt) {
    s16x8 a = *(const s16x8*)(&Olds[mrow + rowA][kt * 32 + quad * 8]);
#pragma unroll
    for (int nt = 0; nt < 8; ++nt) {
      s16x8 bfr = *(const s16x8*)(Wfct + (size_t)(ng + nt * 16 + rowA) * 256 + kt * 32 + quad * 8);
      fc[nt] = __builtin_amdgcn_mfma_f32_16x16x32_bf16(a, bfr, fc[nt], 0, 0, 0);
    }
  }
  float* Ob = out + ((size_t)b * S1_ + s0) * F_;
#pragma unroll
  for (int nt = 0; nt < 8; ++nt) {
    int g = ng + nt * 16 + rowA;
    float bias = bfc[g];
#pragma unroll
    for (int r = 0; r < 4; ++r)
      Ob[(size_t)(mrow + quad * 4 + r) * F_ + g] = fc[nt][r] + bias;
  }
}

extern "C" void kernel_launch(void* const* d_in, const int* in_sizes, int n_in,
                              void* d_out, int out_size, void* d_ws, size_t ws_size,
                              hipStream_t stream) {
  const float* feat1 = (const float*)d_in[0];
  const float* feat2 = (const float*)d_in[1];
  const float* Wq  = (const float*)d_in[2];
  const float* bq  = (const float*)d_in[3];
  const float* Wk  = (const float*)d_in[4];
  const float* bk  = (const float*)d_in[5];
  const float* Wv  = (const float*)d_in[6];
  const float* bv  = (const float*)d_in[7];
  const float* Wfc = (const float*)d_in[8];
  const float* bfc = (const float*)d_in[9];
  float* out = (float*)d_out;
  char* ws = (char*)d_ws;

  // workspace layout (unchanged offsets; AO slab now unused)
  short* Qw   = (short*)(ws);                       // 8 MB  [B][S1][F]
  short* Kw   = (short*)(ws + (size_t)(8u  << 20)); // 8 MB  [B][S2][F]
  short* Vtw  = (short*)(ws + (size_t)(16u << 20)); // 8 MB  [B][F][S2]
  short* Wqt  = (short*)(ws + (size_t)(32u << 20)); // 256KB [F][D]
  short* Wkt  = Wqt + 256 * 512;
  short* Wvt  = Wkt + 256 * 512;
  short* Wfct = Wvt + 256 * 512;                    // [256][256]

  wtrans_kernel<<<dim3(32, 4), 256, 0, stream>>>(Wq, Wk, Wv, Wfc, Wqt, Wkt, Wvt, Wfct);
  proj_kernel<<<dim3(256, 3), 256, 0, stream>>>(feat1, feat2, Wqt, Wkt, Wvt,
                                                bq, bk, bv, Qw, Kw, Vtw);
  flash_kernel<<<dim3(256), 512, 0, stream>>>(Qw, Kw, Vtw, Wfct, bfc, out);
}

// Round 2
// 198.763 us; speedup vs baseline: 1.0108x; 1.0108x over previous
//
#include <hip/hip_runtime.h>
#include <hip/hip_bf16.h>

#define B_ 8
#define S1_ 2048
#define S2_ 2048
#define D_ 512
#define F_ 256

typedef __attribute__((ext_vector_type(4))) float f32x4;
typedef __attribute__((ext_vector_type(8))) short s16x8;
typedef __attribute__((ext_vector_type(4))) short s16x4;

__device__ __forceinline__ short f2bf(float x) {
  union { float f; unsigned u; } v; v.f = x;
  unsigned r = v.u + 0x7fffu + ((v.u >> 16) & 1u);
  return (short)(r >> 16);
}

__device__ __forceinline__ int pk2bf(float a, float b) {
  union { __hip_bfloat162 h; int i; } u;
  u.h = __float22bfloat162_rn(make_float2(a, b));
  return u.i;
}

// ---------------- weight transpose via LDS tile (coalesced both ways) ------
__global__ __launch_bounds__(256) void wtrans_kernel(
    const float* __restrict__ Wq, const float* __restrict__ Wk,
    const float* __restrict__ Wv, const float* __restrict__ Wfc,
    short* __restrict__ Wqt, short* __restrict__ Wkt,
    short* __restrict__ Wvt, short* __restrict__ Wfct) {
  int y = blockIdx.y;
  const float* W; short* Wt; int D;
  if (y == 0)      { W = Wq;  Wt = Wqt;  D = 512; }
  else if (y == 1) { W = Wk;  Wt = Wkt;  D = 512; }
  else if (y == 2) { W = Wv;  Wt = Wvt;  D = 512; }
  else             { W = Wfc; Wt = Wfct; D = 256; }
  int tiles_d = D >> 6;
  int bx = blockIdx.x;
  if (bx >= tiles_d * 4) return;
  int d0 = (bx % tiles_d) * 64, f0 = (bx / tiles_d) * 64;

  __shared__ short Ts[64][68];
  int t = threadIdx.x;
  int r = t >> 2, c16 = (t & 3) * 16;
  {
    const float* src = W + (size_t)(d0 + r) * F_ + f0 + c16;
    f32x4 v0 = *(const f32x4*)(src);
    f32x4 v1 = *(const f32x4*)(src + 4);
    f32x4 v2 = *(const f32x4*)(src + 8);
    f32x4 v3 = *(const f32x4*)(src + 12);
    s16x8 s0, s1;
    ((int*)&s0)[0] = pk2bf(v0[0], v0[1]); ((int*)&s0)[1] = pk2bf(v0[2], v0[3]);
    ((int*)&s0)[2] = pk2bf(v1[0], v1[1]); ((int*)&s0)[3] = pk2bf(v1[2], v1[3]);
    ((int*)&s1)[0] = pk2bf(v2[0], v2[1]); ((int*)&s1)[1] = pk2bf(v2[2], v2[3]);
    ((int*)&s1)[2] = pk2bf(v3[0], v3[1]); ((int*)&s1)[3] = pk2bf(v3[2], v3[3]);
    *(s16x8*)(&Ts[r][c16]) = s0;
    *(s16x8*)(&Ts[r][c16 + 8]) = s1;
  }
  __syncthreads();
  {
    int fr = t >> 2, dc16 = (t & 3) * 16;
    s16x8 o0, o1;
    for (int j = 0; j < 8; ++j) o0[j] = Ts[dc16 + j][fr];
    for (int j = 0; j < 8; ++j) o1[j] = Ts[dc16 + 8 + j][fr];
    short* dst = Wt + (size_t)(f0 + fr) * D + d0 + dc16;
    *(s16x8*)dst = o0;
    *(s16x8*)(dst + 8) = o1;
  }
}

// ---------------- QKV projection: 64 rows x 256 cols (full N), BK=64 ------
// R5 version verbatim: 256 threads, 3 blocks/CU. Proven fastest proj combo.
__global__ __launch_bounds__(256, 3) void proj_kernel(
    const float* __restrict__ feat1, const float* __restrict__ feat2,
    const short* __restrict__ Wqt, const short* __restrict__ Wkt,
    const short* __restrict__ Wvt,
    const float* __restrict__ bq, const float* __restrict__ bk,
    const float* __restrict__ bv,
    short* __restrict__ Qw, short* __restrict__ Kw, short* __restrict__ Vtw) {
  const float* A; const short* Wt; const float* bias; short* outp;
  float scale; int trans;
  if (blockIdx.y == 0)      { A = feat1; Wt = Wqt; bias = bq; outp = Qw;  scale = 0.0625f; trans = 0; }
  else if (blockIdx.y == 1) { A = feat2; Wt = Wkt; bias = bk; outp = Kw;  scale = 1.0f;    trans = 0; }
  else                      { A = feat2; Wt = Wvt; bias = bv; outp = Vtw; scale = 1.0f;    trans = 1; }

  __shared__ __align__(16) short As[64][72];    // A tile 64x64 bf16
  __shared__ __align__(16) short Ws[256][72];   // W tile 256x64 bf16

  int m0 = blockIdx.x * 64;
  int t = threadIdx.x;
  int w = t >> 6, L = t & 63, rowA = L & 15, quad = L >> 4;
  int ar = t >> 2, ac16 = (t & 3) * 16;   // A staging: 4 lanes/row

  f32x4 acc[4][4];
  for (int i = 0; i < 4; ++i)
    for (int j = 0; j < 4; ++j) acc[i][j] = (f32x4){0.f, 0.f, 0.f, 0.f};

  for (int k0 = 0; k0 < D_; k0 += 64) {
    {   // stage A 64x64 fp32->bf16: each thread 16 floats
      const float* src = A + (size_t)(m0 + ar) * D_ + k0 + ac16;
      f32x4 v0 = *(const f32x4*)(src);
      f32x4 v1 = *(const f32x4*)(src + 4);
      f32x4 v2 = *(const f32x4*)(src + 8);
      f32x4 v3 = *(const f32x4*)(src + 12);
      s16x8 s0, s1;
      ((int*)&s0)[0] = pk2bf(v0[0], v0[1]); ((int*)&s0)[1] = pk2bf(v0[2], v0[3]);
      ((int*)&s0)[2] = pk2bf(v1[0], v1[1]); ((int*)&s0)[3] = pk2bf(v1[2], v1[3]);
      ((int*)&s1)[0] = pk2bf(v2[0], v2[1]); ((int*)&s1)[1] = pk2bf(v2[2], v2[3]);
      ((int*)&s1)[2] = pk2bf(v3[0], v3[1]); ((int*)&s1)[3] = pk2bf(v3[2], v3[3]);
      *(s16x8*)(&As[ar][ac16]) = s0;
      *(s16x8*)(&As[ar][ac16 + 8]) = s1;
    }
    for (int p = 0; p < 4; ++p) {   // stage W 256x64: 4 passes of 64 rows
      int r = (t >> 2) + p * 64;
      const short* src = Wt + (size_t)r * D_ + k0 + ac16;
      *(s16x8*)(&Ws[r][ac16]) = *(const s16x8*)(src);
      *(s16x8*)(&Ws[r][ac16 + 8]) = *(const s16x8*)(src + 8);
    }
    __syncthreads();
    for (int kt = 0; kt < 2; ++kt) {
      s16x8 a[4];
      for (int mt = 0; mt < 4; ++mt)
        a[mt] = *(const s16x8*)(&As[mt * 16 + rowA][kt * 32 + quad * 8]);
      for (int nt = 0; nt < 4; ++nt) {
        s16x8 bfr = *(const s16x8*)(&Ws[w * 64 + nt * 16 + rowA][kt * 32 + quad * 8]);
        for (int mt = 0; mt < 4; ++mt)
          acc[mt][nt] = __builtin_amdgcn_mfma_f32_16x16x32_bf16(a[mt], bfr, acc[mt][nt], 0, 0, 0);
      }
    }
    __syncthreads();
  }

  if (!trans) {
    float bn[4];
    for (int nt = 0; nt < 4; ++nt) bn[nt] = bias[w * 64 + nt * 16 + rowA];
    for (int mt = 0; mt < 4; ++mt) {
      int m = m0 + mt * 16 + quad * 4;
      for (int nt = 0; nt < 4; ++nt) {
        int n = w * 64 + nt * 16 + rowA;
        for (int r = 0; r < 4; ++r)
          outp[(size_t)(m + r) * F_ + n] = f2bf((acc[mt][nt][r] + bn[nt]) * scale);
      }
    }
  } else {
    int bb = m0 >> 11;
    int tbase = m0 & (S2_ - 1);
    float bn[4];
    for (int nt = 0; nt < 4; ++nt) bn[nt] = bias[w * 64 + nt * 16 + rowA];
    for (int nt = 0; nt < 4; ++nt) {
      int f = w * 64 + nt * 16 + rowA;
      for (int mt = 0; mt < 4; ++mt) {
        int tt = tbase + mt * 16 + quad * 4;
        s16x4 o;
        for (int r = 0; r < 4; ++r) o[r] = f2bf(acc[mt][nt][r] + bn[nt]);
        *(s16x4*)(outp + ((size_t)bb * F_ + f) * S2_ + tt) = o;
      }
    }
  }
}

// ---------------- flash attention (R8 loop) + fused FC epilogue -----------
// Main loop: R8 verbatim (reg-prefetch staging, padded LDS — proven 58.5us)
// except PV waves retiled 32x128 -> 64x64 (16 LDS reads/iter instead of 20,
// same 32 MFMA). Epilogue: normalized O -> LDS (dead Ks buffer), all 8 waves
// FC-GEMM vs L2-resident Wfct, fp32 out direct. fc_kernel removed.
__global__ __launch_bounds__(512, 2) void flash_kernel(
    const short* __restrict__ Q,    // [B][S1][F] bf16 (scaled)
    const short* __restrict__ K,    // [B][S2][F] bf16
    const short* __restrict__ Vt,   // [B][F][S2] bf16
    const short* __restrict__ Wfct, // [F g][F k] bf16
    const float* __restrict__ bfc,
    float* __restrict__ out) {      // [B][S1][F] fp32
  __shared__ __align__(16) short Ks[2][64][264];   // 67584 B
  __shared__ __align__(16) short Vs[2][256][72];   // 73728 B
  __shared__ __align__(16) short Ps[2][64][72];    // 18432 B
  __shared__ float lfbuf[128];                     // 512 B (total 160256)

  int b = blockIdx.x & 7;            // XCD-aware: batch = block % 8
  int s0 = (blockIdx.x >> 3) * 64;
  int t = threadIdx.x;
  int w = t >> 6, L = t & 63, rowA = L & 15, quad = L >> 4;
  int isS = (w < 4);

  const short* Kb = K + (size_t)b * S2_ * F_;
  const short* Vb = Vt + (size_t)b * F_ * S2_;

  int kr = t >> 5, kc8 = (t & 31) * 8;
  int vr = t >> 3, vc8 = (t & 7) * 8;

  int rs = (w & 1) * 32, cs = ((w >> 1) & 1) * 32;   // S-wave quadrant
  int fgc = (w - 4) * 64;                            // PV-wave column group

  s16x8 qf[2][8];
  if (isS) {
    const short* Qb = Q + ((size_t)b * S1_ + s0 + rs) * F_;
    for (int mt = 0; mt < 2; ++mt)
      for (int kt = 0; kt < 8; ++kt)
        qf[mt][kt] = *(const s16x8*)(Qb + (size_t)(mt * 16 + rowA) * F_ + kt * 32 + quad * 8);
  }
  f32x4 o[4][4];
  for (int i = 0; i < 4; ++i)
    for (int j = 0; j < 4; ++j) o[i][j] = (f32x4){0.f, 0.f, 0.f, 0.f};
  float l_lane[2][4] = {{0.f,0.f,0.f,0.f},{0.f,0.f,0.f,0.f}};

  s16x8 kpre[4], vpre[4];
  for (int p = 0; p < 4; ++p)
    kpre[p] = *(const s16x8*)(Kb + (size_t)(kr + p * 16) * F_ + kc8);
  for (int p = 0; p < 4; ++p)
    *(s16x8*)(&Ks[0][kr + p * 16][kc8]) = kpre[p];
  for (int p = 0; p < 4; ++p)
    kpre[p] = *(const s16x8*)(Kb + (size_t)(64 + kr + p * 16) * F_ + kc8);
  for (int p = 0; p < 4; ++p)
    vpre[p] = *(const s16x8*)(Vb + (size_t)(vr + p * 64) * S2_ + vc8);

  for (int it = 0; it <= 32; ++it) {
    int cb = it & 1;
    __syncthreads();
    if (it < 32) {
      for (int p = 0; p < 4; ++p)
        *(s16x8*)(&Vs[cb][vr + p * 64][vc8]) = vpre[p];
      if (it < 31) {
        for (int p = 0; p < 4; ++p)
          *(s16x8*)(&Ks[1 - cb][kr + p * 16][kc8]) = kpre[p];
        int n0 = (it + 1) * 64;
        for (int p = 0; p < 4; ++p)
          vpre[p] = *(const s16x8*)(Vb + (size_t)(vr + p * 64) * S2_ + n0 + vc8);
      }
      if (it < 30) {
        int n0 = (it + 2) * 64;
        for (int p = 0; p < 4; ++p)
          kpre[p] = *(const s16x8*)(Kb + (size_t)(n0 + kr + p * 16) * F_ + kc8);
      }
    }
    if (isS) {
      if (it < 32) {
        f32x4 s[2][2];
        for (int i = 0; i < 2; ++i)
          for (int j = 0; j < 2; ++j) s[i][j] = (f32x4){0.f, 0.f, 0.f, 0.f};
        for (int kt = 0; kt < 8; ++kt) {
          s16x8 bf0 = *(const s16x8*)(&Ks[cb][cs + rowA][kt * 32 + quad * 8]);
          s16x8 bf1 = *(const s16x8*)(&Ks[cb][cs + 16 + rowA][kt * 32 + quad * 8]);
          for (int mt = 0; mt < 2; ++mt) {
            s[mt][0] = __builtin_amdgcn_mfma_f32_16x16x32_bf16(qf[mt][kt], bf0, s[mt][0], 0, 0, 0);
            s[mt][1] = __builtin_amdgcn_mfma_f32_16x16x32_bf16(qf[mt][kt], bf1, s[mt][1], 0, 0, 0);
          }
        }
        for (int mt = 0; mt < 2; ++mt)
          for (int nt = 0; nt < 2; ++nt)
            for (int r = 0; r < 4; ++r) {
              float p = __expf(s[mt][nt][r]);
              l_lane[mt][r] += p;
              Ps[cb][rs + mt * 16 + quad * 4 + r][cs + nt * 16 + rowA] = f2bf(p);
            }
      }
    } else {
      if (it > 0) {
        int pb = 1 - cb;
        s16x8 pa[4][2];
#pragma unroll
        for (int mt = 0; mt < 4; ++mt)
          for (int kt = 0; kt < 2; ++kt)
            pa[mt][kt] = *(const s16x8*)(&Ps[pb][mt * 16 + rowA][kt * 32 + quad * 8]);
#pragma unroll
        for (int ft = 0; ft < 4; ++ft)
          for (int kt = 0; kt < 2; ++kt) {
            s16x8 vf = *(const s16x8*)(&Vs[pb][fgc + ft * 16 + rowA][kt * 32 + quad * 8]);
            for (int mt = 0; mt < 4; ++mt)
              o[mt][ft] = __builtin_amdgcn_mfma_f32_16x16x32_bf16(pa[mt][kt], vf, o[mt][ft], 0, 0, 0);
          }
      }
    }
  }

  // ---- row-sum reduction (S-waves) into separate lfbuf ----
  if (isS) {
    for (int mt = 0; mt < 2; ++mt)
      for (int r = 0; r < 4; ++r) {
        float x = l_lane[mt][r];
        for (int off = 1; off < 16; off <<= 1)
          x += __shfl_xor(x, off, 64);
        if (rowA == 0)
          lfbuf[((w >> 1) & 1) * 64 + rs + mt * 16 + quad * 4 + r] = x;
      }
  }
  __syncthreads();

  // ---- normalized O (bf16) -> LDS, reusing dead Ks buffer ----
  short (*Olds)[264] = (short (*)[264])(&Ks[0][0][0]);   // 64x264 = 33792 B
  if (!isS) {
    for (int mt = 0; mt < 4; ++mt)
      for (int r = 0; r < 4; ++r) {
        int row = mt * 16 + quad * 4 + r;
        float inv = 1.0f / (lfbuf[row] + lfbuf[64 + row]);
        for (int ft = 0; ft < 4; ++ft)
          Olds[row][fgc + ft * 16 + rowA] = f2bf(o[mt][ft][r] * inv);
      }
  }
  __syncthreads();

  // ---- fused FC: all 8 waves, out[64][256] = Olds[64x256] @ Wfc + bfc ----
  int mrow = (w & 3) * 16;       // 4 M-groups x 2 N-groups
  int ng = (w >> 2) * 128;
  f32x4 fc[8];
  for (int i = 0; i < 8; ++i) fc[i] = (f32x4){0.f, 0.f, 0.f, 0.f};
#pragma unroll
  for (int kt = 0; kt < 8; ++kt) {
    s16x8 a = *(const s16x8*)(&Olds[mrow + rowA][kt * 32 + quad * 8]);
#pragma unroll
    for (int nt = 0; nt < 8; ++nt) {
      s16x8 bfr = *(const s16x8*)(Wfct + (size_t)(ng + nt * 16 + rowA) * 256 + kt * 32 + quad * 8);
      fc[nt] = __builtin_amdgcn_mfma_f32_16x16x32_bf16(a, bfr, fc[nt], 0, 0, 0);
    }
  }
  float* Ob = out + ((size_t)b * S1_ + s0) * F_;
#pragma unroll
  for (int nt = 0; nt < 8; ++nt) {
    int g = ng + nt * 16 + rowA;
    float bias = bfc[g];
#pragma unroll
    for (int r = 0; r < 4; ++r)
      Ob[(size_t)(mrow + quad * 4 + r) * F_ + g] = fc[nt][r] + bias;
  }
}

extern "C" void kernel_launch(void* const* d_in, const int* in_sizes, int n_in,
                              void* d_out, int out_size, void* d_ws, size_t ws_size,
                              hipStream_t stream) {
  const float* feat1 = (const float*)d_in[0];
  const float* feat2 = (const float*)d_in[1];
  const float* Wq  = (const float*)d_in[2];
  const float* bq  = (const float*)d_in[3];
  const float* Wk  = (const float*)d_in[4];
  const float* bk  = (const float*)d_in[5];
  const float* Wv  = (const float*)d_in[6];
  const float* bv  = (const float*)d_in[7];
  const float* Wfc = (const float*)d_in[8];
  const float* bfc = (const float*)d_in[9];
  float* out = (float*)d_out;
  char* ws = (char*)d_ws;

  // workspace layout (AO slab unused after FC fusion; offsets unchanged)
  short* Qw   = (short*)(ws);                       // 8 MB  [B][S1][F]
  short* Kw   = (short*)(ws + (size_t)(8u  << 20)); // 8 MB  [B][S2][F]
  short* Vtw  = (short*)(ws + (size_t)(16u << 20)); // 8 MB  [B][F][S2]
  short* Wqt  = (short*)(ws + (size_t)(32u << 20)); // 256KB [F][D]
  short* Wkt  = Wqt + 256 * 512;
  short* Wvt  = Wkt + 256 * 512;
  short* Wfct = Wvt + 256 * 512;                    // [256][256]

  wtrans_kernel<<<dim3(32, 4), 256, 0, stream>>>(Wq, Wk, Wv, Wfc, Wqt, Wkt, Wvt, Wfct);
  proj_kernel<<<dim3(256, 3), 256, 0, stream>>>(feat1, feat2, Wqt, Wkt, Wvt,
                                                bq, bk, bv, Qw, Kw, Vtw);
  flash_kernel<<<dim3(256), 512, 0, stream>>>(Qw, Kw, Vtw, Wfct, bfc, out);
}

// Round 3
// 195.857 us; speedup vs baseline: 1.0258x; 1.0148x over previous
//
#include <hip/hip_runtime.h>
#include <hip/hip_bf16.h>

#define B_ 8
#define S1_ 2048
#define S2_ 2048
#define D_ 512
#define F_ 256

typedef __attribute__((ext_vector_type(4))) float f32x4;
typedef __attribute__((ext_vector_type(8))) short s16x8;
typedef __attribute__((ext_vector_type(4))) short s16x4;

__device__ __forceinline__ short f2bf(float x) {
  union { float f; unsigned u; } v; v.f = x;
  unsigned r = v.u + 0x7fffu + ((v.u >> 16) & 1u);
  return (short)(r >> 16);
}

__device__ __forceinline__ int pk2bf(float a, float b) {
  union { __hip_bfloat162 h; int i; } u;
  u.h = __float22bfloat162_rn(make_float2(a, b));
  return u.i;
}

// ---------------- weight transpose via LDS tile (coalesced both ways) ------
__global__ __launch_bounds__(256) void wtrans_kernel(
    const float* __restrict__ Wq, const float* __restrict__ Wk,
    const float* __restrict__ Wv, const float* __restrict__ Wfc,
    short* __restrict__ Wqt, short* __restrict__ Wkt,
    short* __restrict__ Wvt, short* __restrict__ Wfct) {
  int y = blockIdx.y;
  const float* W; short* Wt; int D;
  if (y == 0)      { W = Wq;  Wt = Wqt;  D = 512; }
  else if (y == 1) { W = Wk;  Wt = Wkt;  D = 512; }
  else if (y == 2) { W = Wv;  Wt = Wvt;  D = 512; }
  else             { W = Wfc; Wt = Wfct; D = 256; }
  int tiles_d = D >> 6;
  int bx = blockIdx.x;
  if (bx >= tiles_d * 4) return;
  int d0 = (bx % tiles_d) * 64, f0 = (bx / tiles_d) * 64;

  __shared__ short Ts[64][68];
  int t = threadIdx.x;
  int r = t >> 2, c16 = (t & 3) * 16;
  {
    const float* src = W + (size_t)(d0 + r) * F_ + f0 + c16;
    f32x4 v0 = *(const f32x4*)(src);
    f32x4 v1 = *(const f32x4*)(src + 4);
    f32x4 v2 = *(const f32x4*)(src + 8);
    f32x4 v3 = *(const f32x4*)(src + 12);
    s16x8 s0, s1;
    ((int*)&s0)[0] = pk2bf(v0[0], v0[1]); ((int*)&s0)[1] = pk2bf(v0[2], v0[3]);
    ((int*)&s0)[2] = pk2bf(v1[0], v1[1]); ((int*)&s0)[3] = pk2bf(v1[2], v1[3]);
    ((int*)&s1)[0] = pk2bf(v2[0], v2[1]); ((int*)&s1)[1] = pk2bf(v2[2], v2[3]);
    ((int*)&s1)[2] = pk2bf(v3[0], v3[1]); ((int*)&s1)[3] = pk2bf(v3[2], v3[3]);
    *(s16x8*)(&Ts[r][c16]) = s0;
    *(s16x8*)(&Ts[r][c16 + 8]) = s1;
  }
  __syncthreads();
  {
    int fr = t >> 2, dc16 = (t & 3) * 16;
    s16x8 o0, o1;
    for (int j = 0; j < 8; ++j) o0[j] = Ts[dc16 + j][fr];
    for (int j = 0; j < 8; ++j) o1[j] = Ts[dc16 + 8 + j][fr];
    short* dst = Wt + (size_t)(f0 + fr) * D + d0 + dc16;
    *(s16x8*)dst = o0;
    *(s16x8*)(dst + 8) = o1;
  }
}

// ---------------- QKV projection: 64 rows x 256 cols (full N), BK=64 ------
// R5 version verbatim: 256 threads, 3 blocks/CU. Proven fastest proj combo.
__global__ __launch_bounds__(256, 3) void proj_kernel(
    const float* __restrict__ feat1, const float* __restrict__ feat2,
    const short* __restrict__ Wqt, const short* __restrict__ Wkt,
    const short* __restrict__ Wvt,
    const float* __restrict__ bq, const float* __restrict__ bk,
    const float* __restrict__ bv,
    short* __restrict__ Qw, short* __restrict__ Kw, short* __restrict__ Vtw) {
  const float* A; const short* Wt; const float* bias; short* outp;
  float scale; int trans;
  if (blockIdx.y == 0)      { A = feat1; Wt = Wqt; bias = bq; outp = Qw;  scale = 0.0625f; trans = 0; }
  else if (blockIdx.y == 1) { A = feat2; Wt = Wkt; bias = bk; outp = Kw;  scale = 1.0f;    trans = 0; }
  else                      { A = feat2; Wt = Wvt; bias = bv; outp = Vtw; scale = 1.0f;    trans = 1; }

  __shared__ __align__(16) short As[64][72];    // A tile 64x64 bf16
  __shared__ __align__(16) short Ws[256][72];   // W tile 256x64 bf16

  int m0 = blockIdx.x * 64;
  int t = threadIdx.x;
  int w = t >> 6, L = t & 63, rowA = L & 15, quad = L >> 4;
  int ar = t >> 2, ac16 = (t & 3) * 16;   // A staging: 4 lanes/row

  f32x4 acc[4][4];
  for (int i = 0; i < 4; ++i)
    for (int j = 0; j < 4; ++j) acc[i][j] = (f32x4){0.f, 0.f, 0.f, 0.f};

  for (int k0 = 0; k0 < D_; k0 += 64) {
    {   // stage A 64x64 fp32->bf16: each thread 16 floats
      const float* src = A + (size_t)(m0 + ar) * D_ + k0 + ac16;
      f32x4 v0 = *(const f32x4*)(src);
      f32x4 v1 = *(const f32x4*)(src + 4);
      f32x4 v2 = *(const f32x4*)(src + 8);
      f32x4 v3 = *(const f32x4*)(src + 12);
      s16x8 s0, s1;
      ((int*)&s0)[0] = pk2bf(v0[0], v0[1]); ((int*)&s0)[1] = pk2bf(v0[2], v0[3]);
      ((int*)&s0)[2] = pk2bf(v1[0], v1[1]); ((int*)&s0)[3] = pk2bf(v1[2], v1[3]);
      ((int*)&s1)[0] = pk2bf(v2[0], v2[1]); ((int*)&s1)[1] = pk2bf(v2[2], v2[3]);
      ((int*)&s1)[2] = pk2bf(v3[0], v3[1]); ((int*)&s1)[3] = pk2bf(v3[2], v3[3]);
      *(s16x8*)(&As[ar][ac16]) = s0;
      *(s16x8*)(&As[ar][ac16 + 8]) = s1;
    }
    for (int p = 0; p < 4; ++p) {   // stage W 256x64: 4 passes of 64 rows
      int r = (t >> 2) + p * 64;
      const short* src = Wt + (size_t)r * D_ + k0 + ac16;
      *(s16x8*)(&Ws[r][ac16]) = *(const s16x8*)(src);
      *(s16x8*)(&Ws[r][ac16 + 8]) = *(const s16x8*)(src + 8);
    }
    __syncthreads();
    for (int kt = 0; kt < 2; ++kt) {
      s16x8 a[4];
      for (int mt = 0; mt < 4; ++mt)
        a[mt] = *(const s16x8*)(&As[mt * 16 + rowA][kt * 32 + quad * 8]);
      for (int nt = 0; nt < 4; ++nt) {
        s16x8 bfr = *(const s16x8*)(&Ws[w * 64 + nt * 16 + rowA][kt * 32 + quad * 8]);
        for (int mt = 0; mt < 4; ++mt)
          acc[mt][nt] = __builtin_amdgcn_mfma_f32_16x16x32_bf16(a[mt], bfr, acc[mt][nt], 0, 0, 0);
      }
    }
    __syncthreads();
  }

  if (!trans) {
    float bn[4];
    for (int nt = 0; nt < 4; ++nt) bn[nt] = bias[w * 64 + nt * 16 + rowA];
    for (int mt = 0; mt < 4; ++mt) {
      int m = m0 + mt * 16 + quad * 4;
      for (int nt = 0; nt < 4; ++nt) {
        int n = w * 64 + nt * 16 + rowA;
        for (int r = 0; r < 4; ++r)
          outp[(size_t)(m + r) * F_ + n] = f2bf((acc[mt][nt][r] + bn[nt]) * scale);
      }
    }
  } else {
    int bb = m0 >> 11;
    int tbase = m0 & (S2_ - 1);
    float bn[4];
    for (int nt = 0; nt < 4; ++nt) bn[nt] = bias[w * 64 + nt * 16 + rowA];
    for (int nt = 0; nt < 4; ++nt) {
      int f = w * 64 + nt * 16 + rowA;
      for (int mt = 0; mt < 4; ++mt) {
        int tt = tbase + mt * 16 + quad * 4;
        s16x4 o;
        for (int r = 0; r < 4; ++r) o[r] = f2bf(acc[mt][nt][r] + bn[nt]);
        *(s16x4*)(outp + ((size_t)bb * F_ + f) * S2_ + tt) = o;
      }
    }
  }
}

// ---------------- flash attention: R0 main loop VERBATIM + FC epilogue ----
// Single-variable experiment vs R2: PV tiling restored to the proven 32x128
// (o[2][8], pa[2][2], 20 LDS reads/iter). Only the FC epilogue is kept.
// If this lands ~63-67us the R1/R2 regression was the 64x64 retile; if it
// stays ~85 the epilogue is implicated.
__global__ __launch_bounds__(512, 2) void flash_kernel(
    const short* __restrict__ Q,    // [B][S1][F] bf16 (scaled)
    const short* __restrict__ K,    // [B][S2][F] bf16
    const short* __restrict__ Vt,   // [B][F][S2] bf16
    const short* __restrict__ Wfct, // [F g][F k] bf16
    const float* __restrict__ bfc,
    float* __restrict__ out) {      // [B][S1][F] fp32
  __shared__ __align__(16) short Ks[2][64][264];   // 67584 B
  __shared__ __align__(16) short Vs[2][256][72];   // 73728 B
  __shared__ __align__(16) short Ps[2][64][72];    // 18432 B
  __shared__ float lfbuf[128];                     // 512 B (total 160256)

  int b = blockIdx.x & 7;            // XCD-aware: batch = block % 8
  int s0 = (blockIdx.x >> 3) * 64;
  int t = threadIdx.x;
  int w = t >> 6, L = t & 63, rowA = L & 15, quad = L >> 4;
  int isS = (w < 4);

  const short* Kb = K + (size_t)b * S2_ * F_;
  const short* Vb = Vt + (size_t)b * F_ * S2_;

  int kr = t >> 5, kc8 = (t & 31) * 8;
  int vr = t >> 3, vc8 = (t & 7) * 8;

  int rs = (w & 1) * 32, cs = ((w >> 1) & 1) * 32;   // S-wave quadrant
  int mg = (w - 4) & 1, fg = ((w - 4) >> 1) & 1;     // PV-wave tile (R0)

  s16x8 qf[2][8];
  if (isS) {
    const short* Qb = Q + ((size_t)b * S1_ + s0 + rs) * F_;
    for (int mt = 0; mt < 2; ++mt)
      for (int kt = 0; kt < 8; ++kt)
        qf[mt][kt] = *(const s16x8*)(Qb + (size_t)(mt * 16 + rowA) * F_ + kt * 32 + quad * 8);
  }
  f32x4 o[2][8];
  for (int i = 0; i < 2; ++i)
    for (int j = 0; j < 8; ++j) o[i][j] = (f32x4){0.f, 0.f, 0.f, 0.f};
  float l_lane[2][4] = {{0.f,0.f,0.f,0.f},{0.f,0.f,0.f,0.f}};

  s16x8 kpre[4], vpre[4];
  for (int p = 0; p < 4; ++p)
    kpre[p] = *(const s16x8*)(Kb + (size_t)(kr + p * 16) * F_ + kc8);
  for (int p = 0; p < 4; ++p)
    *(s16x8*)(&Ks[0][kr + p * 16][kc8]) = kpre[p];
  for (int p = 0; p < 4; ++p)
    kpre[p] = *(const s16x8*)(Kb + (size_t)(64 + kr + p * 16) * F_ + kc8);
  for (int p = 0; p < 4; ++p)
    vpre[p] = *(const s16x8*)(Vb + (size_t)(vr + p * 64) * S2_ + vc8);

  for (int it = 0; it <= 32; ++it) {
    int cb = it & 1;
    __syncthreads();
    if (it < 32) {
      for (int p = 0; p < 4; ++p)
        *(s16x8*)(&Vs[cb][vr + p * 64][vc8]) = vpre[p];
      if (it < 31) {
        for (int p = 0; p < 4; ++p)
          *(s16x8*)(&Ks[1 - cb][kr + p * 16][kc8]) = kpre[p];
        int n0 = (it + 1) * 64;
        for (int p = 0; p < 4; ++p)
          vpre[p] = *(const s16x8*)(Vb + (size_t)(vr + p * 64) * S2_ + n0 + vc8);
      }
      if (it < 30) {
        int n0 = (it + 2) * 64;
        for (int p = 0; p < 4; ++p)
          kpre[p] = *(const s16x8*)(Kb + (size_t)(n0 + kr + p * 16) * F_ + kc8);
      }
    }
    if (isS) {
      if (it < 32) {
        f32x4 s[2][2];
        for (int i = 0; i < 2; ++i)
          for (int j = 0; j < 2; ++j) s[i][j] = (f32x4){0.f, 0.f, 0.f, 0.f};
        for (int kt = 0; kt < 8; ++kt) {
          s16x8 bf0 = *(const s16x8*)(&Ks[cb][cs + rowA][kt * 32 + quad * 8]);
          s16x8 bf1 = *(const s16x8*)(&Ks[cb][cs + 16 + rowA][kt * 32 + quad * 8]);
          for (int mt = 0; mt < 2; ++mt) {
            s[mt][0] = __builtin_amdgcn_mfma_f32_16x16x32_bf16(qf[mt][kt], bf0, s[mt][0], 0, 0, 0);
            s[mt][1] = __builtin_amdgcn_mfma_f32_16x16x32_bf16(qf[mt][kt], bf1, s[mt][1], 0, 0, 0);
          }
        }
        for (int mt = 0; mt < 2; ++mt)
          for (int nt = 0; nt < 2; ++nt)
            for (int r = 0; r < 4; ++r) {
              float p = __expf(s[mt][nt][r]);
              l_lane[mt][r] += p;
              Ps[cb][rs + mt * 16 + quad * 4 + r][cs + nt * 16 + rowA] = f2bf(p);
            }
      }
    } else {
      if (it > 0) {
        int pb = 1 - cb;
        s16x8 pa[2][2];
        for (int mt = 0; mt < 2; ++mt)
          for (int kt = 0; kt < 2; ++kt)
            pa[mt][kt] = *(const s16x8*)(&Ps[pb][mg * 32 + mt * 16 + rowA][kt * 32 + quad * 8]);
        for (int ft = 0; ft < 8; ++ft)
          for (int kt = 0; kt < 2; ++kt) {
            s16x8 vf = *(const s16x8*)(&Vs[pb][fg * 128 + ft * 16 + rowA][kt * 32 + quad * 8]);
            for (int mt = 0; mt < 2; ++mt)
              o[mt][ft] = __builtin_amdgcn_mfma_f32_16x16x32_bf16(pa[mt][kt], vf, o[mt][ft], 0, 0, 0);
          }
      }
    }
  }

  // ---- row-sum reduction (S-waves) into lfbuf ----
  if (isS) {
    for (int mt = 0; mt < 2; ++mt)
      for (int r = 0; r < 4; ++r) {
        float x = l_lane[mt][r];
        for (int off = 1; off < 16; off <<= 1)
          x += __shfl_xor(x, off, 64);
        if (rowA == 0)
          lfbuf[((w >> 1) & 1) * 64 + rs + mt * 16 + quad * 4 + r] = x;
      }
  }
  __syncthreads();

  // ---- normalized O (bf16) -> LDS, reusing dead Ks buffer ----
  // PV wave owns rows mg*32+{0..31}, cols fg*128+{0..127} (R0 layout).
  short (*Olds)[264] = (short (*)[264])(&Ks[0][0][0]);   // 64x264 = 33792 B
  if (!isS) {
    for (int mt = 0; mt < 2; ++mt)
      for (int r = 0; r < 4; ++r) {
        int row = mg * 32 + mt * 16 + quad * 4 + r;
        float inv = 1.0f / (lfbuf[row] + lfbuf[64 + row]);
        for (int ft = 0; ft < 8; ++ft)
          Olds[row][fg * 128 + ft * 16 + rowA] = f2bf(o[mt][ft][r] * inv);
      }
  }
  __syncthreads();

  // ---- fused FC: all 8 waves, out[64][256] = Olds[64x256] @ Wfc + bfc ----
  int mrow = (w & 3) * 16;       // 4 M-groups x 2 N-groups
  int ng = (w >> 2) * 128;
  f32x4 fc[8];
  for (int i = 0; i < 8; ++i) fc[i] = (f32x4){0.f, 0.f, 0.f, 0.f};
#pragma unroll
  for (int kt = 0; kt < 8; ++kt) {
    s16x8 a = *(const s16x8*)(&Olds[mrow + rowA][kt * 32 + quad * 8]);
#pragma unroll
    for (int nt = 0; nt < 8; ++nt) {
      s16x8 bfr = *(const s16x8*)(Wfct + (size_t)(ng + nt * 16 + rowA) * 256 + kt * 32 + quad * 8);
      fc[nt] = __builtin_amdgcn_mfma_f32_16x16x32_bf16(a, bfr, fc[nt], 0, 0, 0);
    }
  }
  float* Ob = out + ((size_t)b * S1_ + s0) * F_;
#pragma unroll
  for (int nt = 0; nt < 8; ++nt) {
    int g = ng + nt * 16 + rowA;
    float bias = bfc[g];
#pragma unroll
    for (int r = 0; r < 4; ++r)
      Ob[(size_t)(mrow + quad * 4 + r) * F_ + g] = fc[nt][r] + bias;
  }
}

extern "C" void kernel_launch(void* const* d_in, const int* in_sizes, int n_in,
                              void* d_out, int out_size, void* d_ws, size_t ws_size,
                              hipStream_t stream) {
  const float* feat1 = (const float*)d_in[0];
  const float* feat2 = (const float*)d_in[1];
  const float* Wq  = (const float*)d_in[2];
  const float* bq  = (const float*)d_in[3];
  const float* Wk  = (const float*)d_in[4];
  const float* bk  = (const float*)d_in[5];
  const float* Wv  = (const float*)d_in[6];
  const float* bv  = (const float*)d_in[7];
  const float* Wfc = (const float*)d_in[8];
  const float* bfc = (const float*)d_in[9];
  float* out = (float*)d_out;
  char* ws = (char*)d_ws;

  // workspace layout (AO slab unused after FC fusion; offsets unchanged)
  short* Qw   = (short*)(ws);                       // 8 MB  [B][S1][F]
  short* Kw   = (short*)(ws + (size_t)(8u  << 20)); // 8 MB  [B][S2][F]
  short* Vtw  = (short*)(ws + (size_t)(16u << 20)); // 8 MB  [B][F][S2]
  short* Wqt  = (short*)(ws + (size_t)(32u << 20)); // 256KB [F][D]
  short* Wkt  = Wqt + 256 * 512;
  short* Wvt  = Wkt + 256 * 512;
  short* Wfct = Wvt + 256 * 512;                    // [256][256]

  wtrans_kernel<<<dim3(32, 4), 256, 0, stream>>>(Wq, Wk, Wv, Wfc, Wqt, Wkt, Wvt, Wfct);
  proj_kernel<<<dim3(256, 3), 256, 0, stream>>>(feat1, feat2, Wqt, Wkt, Wvt,
                                                bq, bk, bv, Qw, Kw, Vtw);
  flash_kernel<<<dim3(256), 512, 0, stream>>>(Qw, Kw, Vtw, Wfct, bfc, out);
}

// Round 4
// 192.473 us; speedup vs baseline: 1.0438x; 1.0176x over previous
//
#include <hip/hip_runtime.h>
#include <hip/hip_bf16.h>

#define B_ 8
#define S1_ 2048
#define S2_ 2048
#define D_ 512
#define F_ 256

typedef __attribute__((ext_vector_type(4))) float f32x4;
typedef __attribute__((ext_vector_type(8))) short s16x8;
typedef __attribute__((ext_vector_type(4))) short s16x4;

__device__ __forceinline__ short f2bf(float x) {
  union { float f; unsigned u; } v; v.f = x;
  unsigned r = v.u + 0x7fffu + ((v.u >> 16) & 1u);
  return (short)(r >> 16);
}

__device__ __forceinline__ int pk2bf(float a, float b) {
  union { __hip_bfloat162 h; int i; } u;
  u.h = __float22bfloat162_rn(make_float2(a, b));
  return u.i;
}

// ---------------- weight transpose via LDS tile (coalesced both ways) ------
__global__ __launch_bounds__(256) void wtrans_kernel(
    const float* __restrict__ Wq, const float* __restrict__ Wk,
    const float* __restrict__ Wv, const float* __restrict__ Wfc,
    short* __restrict__ Wqt, short* __restrict__ Wkt,
    short* __restrict__ Wvt, short* __restrict__ Wfct) {
  int y = blockIdx.y;
  const float* W; short* Wt; int D;
  if (y == 0)      { W = Wq;  Wt = Wqt;  D = 512; }
  else if (y == 1) { W = Wk;  Wt = Wkt;  D = 512; }
  else if (y == 2) { W = Wv;  Wt = Wvt;  D = 512; }
  else             { W = Wfc; Wt = Wfct; D = 256; }
  int tiles_d = D >> 6;
  int bx = blockIdx.x;
  if (bx >= tiles_d * 4) return;
  int d0 = (bx % tiles_d) * 64, f0 = (bx / tiles_d) * 64;

  __shared__ short Ts[64][68];
  int t = threadIdx.x;
  int r = t >> 2, c16 = (t & 3) * 16;
  {
    const float* src = W + (size_t)(d0 + r) * F_ + f0 + c16;
    f32x4 v0 = *(const f32x4*)(src);
    f32x4 v1 = *(const f32x4*)(src + 4);
    f32x4 v2 = *(const f32x4*)(src + 8);
    f32x4 v3 = *(const f32x4*)(src + 12);
    s16x8 s0, s1;
    ((int*)&s0)[0] = pk2bf(v0[0], v0[1]); ((int*)&s0)[1] = pk2bf(v0[2], v0[3]);
    ((int*)&s0)[2] = pk2bf(v1[0], v1[1]); ((int*)&s0)[3] = pk2bf(v1[2], v1[3]);
    ((int*)&s1)[0] = pk2bf(v2[0], v2[1]); ((int*)&s1)[1] = pk2bf(v2[2], v2[3]);
    ((int*)&s1)[2] = pk2bf(v3[0], v3[1]); ((int*)&s1)[3] = pk2bf(v3[2], v3[3]);
    *(s16x8*)(&Ts[r][c16]) = s0;
    *(s16x8*)(&Ts[r][c16 + 8]) = s1;
  }
  __syncthreads();
  {
    int fr = t >> 2, dc16 = (t & 3) * 16;
    s16x8 o0, o1;
    for (int j = 0; j < 8; ++j) o0[j] = Ts[dc16 + j][fr];
    for (int j = 0; j < 8; ++j) o1[j] = Ts[dc16 + 8 + j][fr];
    short* dst = Wt + (size_t)(f0 + fr) * D + d0 + dc16;
    *(s16x8*)dst = o0;
    *(s16x8*)(dst + 8) = o1;
  }
}

// ---------------- QKV projection v2: double-buffered, reg-prefetch --------
// Same tiling as proven R5 proj (64 rows x 256 cols, 4 waves, 3 blocks/CU)
// but BK=32 with 2x LDS buffers (51.2 KB total) and flash-style register
// prefetch: next tile's global loads issue BEFORE the compute phase, one
// barrier per K-iter. Removes the stage->barrier->compute serialization.
__global__ __launch_bounds__(256, 3) void proj_kernel(
    const float* __restrict__ feat1, const float* __restrict__ feat2,
    const short* __restrict__ Wqt, const short* __restrict__ Wkt,
    const short* __restrict__ Wvt,
    const float* __restrict__ bq, const float* __restrict__ bk,
    const float* __restrict__ bv,
    short* __restrict__ Qw, short* __restrict__ Kw, short* __restrict__ Vtw) {
  const float* A; const short* Wt; const float* bias; short* outp;
  float scale; int trans;
  if (blockIdx.y == 0)      { A = feat1; Wt = Wqt; bias = bq; outp = Qw;  scale = 0.0625f; trans = 0; }
  else if (blockIdx.y == 1) { A = feat2; Wt = Wkt; bias = bk; outp = Kw;  scale = 1.0f;    trans = 0; }
  else                      { A = feat2; Wt = Wvt; bias = bv; outp = Vtw; scale = 1.0f;    trans = 1; }

  __shared__ __align__(16) short As[2][64][40];    // 2 x 64x32 bf16 (+pad)
  __shared__ __align__(16) short Ws[2][256][40];   // 2 x 256x32 bf16 (+pad)

  int m0 = blockIdx.x * 64;
  int t = threadIdx.x;
  int w = t >> 6, L = t & 63, rowA = L & 15, quad = L >> 4;
  int sr = t >> 2, sc8 = (t & 3) * 8;   // staging: 4 lanes/row, 8 elems/lane

  f32x4 acc[4][4];
  for (int i = 0; i < 4; ++i)
    for (int j = 0; j < 4; ++j) acc[i][j] = (f32x4){0.f, 0.f, 0.f, 0.f};

  // prefetch k=0 into registers
  f32x4 a0, a1;
  s16x8 wp[4];
  {
    const float* src = A + (size_t)(m0 + sr) * D_ + sc8;
    a0 = *(const f32x4*)(src);
    a1 = *(const f32x4*)(src + 4);
    for (int p = 0; p < 4; ++p)
      wp[p] = *(const s16x8*)(Wt + (size_t)(sr + p * 64) * D_ + sc8);
  }

  for (int k = 0; k < 16; ++k) {
    int cur = k & 1;
    {   // write prefetched tile k into buf[cur]
      s16x8 s;
      ((int*)&s)[0] = pk2bf(a0[0], a0[1]); ((int*)&s)[1] = pk2bf(a0[2], a0[3]);
      ((int*)&s)[2] = pk2bf(a1[0], a1[1]); ((int*)&s)[3] = pk2bf(a1[2], a1[3]);
      *(s16x8*)(&As[cur][sr][sc8]) = s;
      for (int p = 0; p < 4; ++p)
        *(s16x8*)(&Ws[cur][sr + p * 64][sc8]) = wp[p];
    }
    __syncthreads();                     // buf[cur] ready for all waves
    if (k < 15) {                        // issue k+1 loads before compute
      int k0 = (k + 1) * 32;
      const float* src = A + (size_t)(m0 + sr) * D_ + k0 + sc8;
      a0 = *(const f32x4*)(src);
      a1 = *(const f32x4*)(src + 4);
      for (int p = 0; p < 4; ++p)
        wp[p] = *(const s16x8*)(Wt + (size_t)(sr + p * 64) * D_ + k0 + sc8);
    }
    s16x8 a[4];
    for (int mt = 0; mt < 4; ++mt)
      a[mt] = *(const s16x8*)(&As[cur][mt * 16 + rowA][quad * 8]);
    for (int nt = 0; nt < 4; ++nt) {
      s16x8 bfr = *(const s16x8*)(&Ws[cur][w * 64 + nt * 16 + rowA][quad * 8]);
      for (int mt = 0; mt < 4; ++mt)
        acc[mt][nt] = __builtin_amdgcn_mfma_f32_16x16x32_bf16(a[mt], bfr, acc[mt][nt], 0, 0, 0);
    }
    // next iter writes buf[1-cur]; no race with this iter's buf[cur] reads
  }

  if (!trans) {
    float bn[4];
    for (int nt = 0; nt < 4; ++nt) bn[nt] = bias[w * 64 + nt * 16 + rowA];
    for (int mt = 0; mt < 4; ++mt) {
      int m = m0 + mt * 16 + quad * 4;
      for (int nt = 0; nt < 4; ++nt) {
        int n = w * 64 + nt * 16 + rowA;
        for (int r = 0; r < 4; ++r)
          outp[(size_t)(m + r) * F_ + n] = f2bf((acc[mt][nt][r] + bn[nt]) * scale);
      }
    }
  } else {
    int bb = m0 >> 11;
    int tbase = m0 & (S2_ - 1);
    float bn[4];
    for (int nt = 0; nt < 4; ++nt) bn[nt] = bias[w * 64 + nt * 16 + rowA];
    for (int nt = 0; nt < 4; ++nt) {
      int f = w * 64 + nt * 16 + rowA;
      for (int mt = 0; mt < 4; ++mt) {
        int tt = tbase + mt * 16 + quad * 4;
        s16x4 o;
        for (int r = 0; r < 4; ++r) o[r] = f2bf(acc[mt][nt][r] + bn[nt]);
        *(s16x4*)(outp + ((size_t)bb * F_ + f) * S2_ + tt) = o;
      }
    }
  }
}

// ---------------- flash attention: wave-specialized + XCD swizzle ---------
// R0 verbatim (proven 58.5 us).
__global__ __launch_bounds__(512, 2) void flash_kernel(
    const short* __restrict__ Q,    // [B][S1][F] bf16 (scaled)
    const short* __restrict__ K,    // [B][S2][F] bf16
    const short* __restrict__ Vt,   // [B][F][S2] bf16
    short* __restrict__ O) {        // [B][S1][F] bf16 (normalized)
  __shared__ __align__(16) short Ks[2][64][264];   // 67584 B
  __shared__ __align__(16) short Vs[2][256][72];   // 73728 B
  __shared__ __align__(16) short Ps[2][64][72];    // 18432 B  (sum 159744)

  int b = blockIdx.x & 7;            // XCD-aware: batch = block % 8
  int s0 = (blockIdx.x >> 3) * 64;
  int t = threadIdx.x;
  int w = t >> 6, L = t & 63, rowA = L & 15, quad = L >> 4;
  int isS = (w < 4);

  const short* Kb = K + (size_t)b * S2_ * F_;
  const short* Vb = Vt + (size_t)b * F_ * S2_;

  int kr = t >> 5, kc8 = (t & 31) * 8;
  int vr = t >> 3, vc8 = (t & 7) * 8;

  int rs = (w & 1) * 32, cs = ((w >> 1) & 1) * 32;   // S-wave quadrant
  int mg = (w - 4) & 1, fg = ((w - 4) >> 1) & 1;     // PV-wave tile

  s16x8 qf[2][8];
  if (isS) {
    const short* Qb = Q + ((size_t)b * S1_ + s0 + rs) * F_;
    for (int mt = 0; mt < 2; ++mt)
      for (int kt = 0; kt < 8; ++kt)
        qf[mt][kt] = *(const s16x8*)(Qb + (size_t)(mt * 16 + rowA) * F_ + kt * 32 + quad * 8);
  }
  f32x4 o[2][8];
  for (int i = 0; i < 2; ++i)
    for (int j = 0; j < 8; ++j) o[i][j] = (f32x4){0.f, 0.f, 0.f, 0.f};
  float l_lane[2][4] = {{0.f,0.f,0.f,0.f},{0.f,0.f,0.f,0.f}};

  s16x8 kpre[4], vpre[4];
  for (int p = 0; p < 4; ++p)
    kpre[p] = *(const s16x8*)(Kb + (size_t)(kr + p * 16) * F_ + kc8);
  for (int p = 0; p < 4; ++p)
    *(s16x8*)(&Ks[0][kr + p * 16][kc8]) = kpre[p];
  for (int p = 0; p < 4; ++p)
    kpre[p] = *(const s16x8*)(Kb + (size_t)(64 + kr + p * 16) * F_ + kc8);
  for (int p = 0; p < 4; ++p)
    vpre[p] = *(const s16x8*)(Vb + (size_t)(vr + p * 64) * S2_ + vc8);

  for (int it = 0; it <= 32; ++it) {
    int cb = it & 1;
    __syncthreads();
    if (it < 32) {
      for (int p = 0; p < 4; ++p)
        *(s16x8*)(&Vs[cb][vr + p * 64][vc8]) = vpre[p];
      if (it < 31) {
        for (int p = 0; p < 4; ++p)
          *(s16x8*)(&Ks[1 - cb][kr + p * 16][kc8]) = kpre[p];
        int n0 = (it + 1) * 64;
        for (int p = 0; p < 4; ++p)
          vpre[p] = *(const s16x8*)(Vb + (size_t)(vr + p * 64) * S2_ + n0 + vc8);
      }
      if (it < 30) {
        int n0 = (it + 2) * 64;
        for (int p = 0; p < 4; ++p)
          kpre[p] = *(const s16x8*)(Kb + (size_t)(n0 + kr + p * 16) * F_ + kc8);
      }
    }
    if (isS) {
      if (it < 32) {
        f32x4 s[2][2];
        for (int i = 0; i < 2; ++i)
          for (int j = 0; j < 2; ++j) s[i][j] = (f32x4){0.f, 0.f, 0.f, 0.f};
        for (int kt = 0; kt < 8; ++kt) {
          s16x8 bf0 = *(const s16x8*)(&Ks[cb][cs + rowA][kt * 32 + quad * 8]);
          s16x8 bf1 = *(const s16x8*)(&Ks[cb][cs + 16 + rowA][kt * 32 + quad * 8]);
          for (int mt = 0; mt < 2; ++mt) {
            s[mt][0] = __builtin_amdgcn_mfma_f32_16x16x32_bf16(qf[mt][kt], bf0, s[mt][0], 0, 0, 0);
            s[mt][1] = __builtin_amdgcn_mfma_f32_16x16x32_bf16(qf[mt][kt], bf1, s[mt][1], 0, 0, 0);
          }
        }
        for (int mt = 0; mt < 2; ++mt)
          for (int nt = 0; nt < 2; ++nt)
            for (int r = 0; r < 4; ++r) {
              float p = __expf(s[mt][nt][r]);
              l_lane[mt][r] += p;
              Ps[cb][rs + mt * 16 + quad * 4 + r][cs + nt * 16 + rowA] = f2bf(p);
            }
      }
    } else {
      if (it > 0) {
        int pb = 1 - cb;
        s16x8 pa[2][2];
        for (int mt = 0; mt < 2; ++mt)
          for (int kt = 0; kt < 2; ++kt)
            pa[mt][kt] = *(const s16x8*)(&Ps[pb][mg * 32 + mt * 16 + rowA][kt * 32 + quad * 8]);
        for (int ft = 0; ft < 8; ++ft)
          for (int kt = 0; kt < 2; ++kt) {
            s16x8 vf = *(const s16x8*)(&Vs[pb][fg * 128 + ft * 16 + rowA][kt * 32 + quad * 8]);
            for (int mt = 0; mt < 2; ++mt)
              o[mt][ft] = __builtin_amdgcn_mfma_f32_16x16x32_bf16(pa[mt][kt], vf, o[mt][ft], 0, 0, 0);
          }
      }
    }
  }

  float* lf = (float*)&Ks[0][0][0];   // [2 col-halves][64 rows]
  if (isS) {
    for (int mt = 0; mt < 2; ++mt)
      for (int r = 0; r < 4; ++r) {
        float x = l_lane[mt][r];
        for (int off = 1; off < 16; off <<= 1)
          x += __shfl_xor(x, off, 64);
        if (rowA == 0)
          lf[((w >> 1) & 1) * 64 + rs + mt * 16 + quad * 4 + r] = x;
      }
  }
  __syncthreads();
  if (!isS) {
    short* Ob = O + ((size_t)b * S1_ + s0) * F_;
    for (int mt = 0; mt < 2; ++mt)
      for (int r = 0; r < 4; ++r) {
        int row = mg * 32 + mt * 16 + quad * 4 + r;
        float inv = 1.0f / (lf[row] + lf[64 + row]);
        for (int ft = 0; ft < 8; ++ft)
          Ob[(size_t)row * F_ + fg * 128 + ft * 16 + rowA] = f2bf(o[mt][ft][r] * inv);
      }
  }
}

// ---------------- FC: 64x128 tile, 512 blocks (2/CU), prefetched ----------
__global__ __launch_bounds__(256) void fc_kernel(
    const short* __restrict__ AO,   // [16384][256] bf16
    const short* __restrict__ Wt,   // [256 g][256 k] bf16
    const float* __restrict__ bias,
    float* __restrict__ out) {
  __shared__ __align__(16) short As[64][72];    // 9216 B
  __shared__ __align__(16) short Ws[128][72];   // 18432 B (27.6 KB total)

  int m0 = blockIdx.x * 64;
  int n0 = blockIdx.y * 128;
  int t = threadIdx.x;
  int w = t >> 6, L = t & 63, rowA = L & 15, quad = L >> 4;
  int wy = w & 1, wx = w >> 1;   // 32-row half, 64-col half

  int ar = t >> 2, ac16 = (t & 3) * 16;   // A staging: 16 shorts/thread
  int wr = t >> 1, wc32 = (t & 1) * 32;   // W staging: 32 shorts/thread

  s16x8 apre[2], wpre[4];
  {   // prologue k0 = 0
    const short* asrc = AO + (size_t)(m0 + ar) * F_ + ac16;
    apre[0] = *(const s16x8*)(asrc);
    apre[1] = *(const s16x8*)(asrc + 8);
    const short* wsrc = Wt + (size_t)(n0 + wr) * F_ + wc32;
    for (int j = 0; j < 4; ++j) wpre[j] = *(const s16x8*)(wsrc + j * 8);
  }

  f32x4 acc[2][4];
  for (int i = 0; i < 2; ++i)
    for (int j = 0; j < 4; ++j) acc[i][j] = (f32x4){0.f, 0.f, 0.f, 0.f};

  for (int k0 = 0; k0 < F_; k0 += 64) {
    *(s16x8*)(&As[ar][ac16]) = apre[0];
    *(s16x8*)(&As[ar][ac16 + 8]) = apre[1];
    for (int j = 0; j < 4; ++j) *(s16x8*)(&Ws[wr][wc32 + j * 8]) = wpre[j];
    __syncthreads();
    if (k0 + 64 < F_) {   // prefetch next slab
      const short* asrc = AO + (size_t)(m0 + ar) * F_ + k0 + 64 + ac16;
      apre[0] = *(const s16x8*)(asrc);
      apre[1] = *(const s16x8*)(asrc + 8);
      const short* wsrc = Wt + (size_t)(n0 + wr) * F_ + k0 + 64 + wc32;
      for (int j = 0; j < 4; ++j) wpre[j] = *(const s16x8*)(wsrc + j * 8);
    }
    for (int kt = 0; kt < 2; ++kt) {
      s16x8 a[2];
      for (int mt = 0; mt < 2; ++mt)
        a[mt] = *(const s16x8*)(&As[wy * 32 + mt * 16 + rowA][kt * 32 + quad * 8]);
      for (int nt = 0; nt < 4; ++nt) {
        s16x8 bfr = *(const s16x8*)(&Ws[wx * 64 + nt * 16 + rowA][kt * 32 + quad * 8]);
        for (int mt = 0; mt < 2; ++mt)
          acc[mt][nt] = __builtin_amdgcn_mfma_f32_16x16x32_bf16(a[mt], bfr, acc[mt][nt], 0, 0, 0);
      }
    }
    __syncthreads();
  }

  float bn[4];
  for (int nt = 0; nt < 4; ++nt) bn[nt] = bias[n0 + wx * 64 + nt * 16 + rowA];
  for (int mt = 0; mt < 2; ++mt) {
    int m = m0 + wy * 32 + mt * 16 + quad * 4;
    for (int nt = 0; nt < 4; ++nt) {
      int n = n0 + wx * 64 + nt * 16 + rowA;
      for (int r = 0; r < 4; ++r)
        out[(size_t)(m + r) * F_ + n] = acc[mt][nt][r] + bn[nt];
    }
  }
}

extern "C" void kernel_launch(void* const* d_in, const int* in_sizes, int n_in,
                              void* d_out, int out_size, void* d_ws, size_t ws_size,
                              hipStream_t stream) {
  const float* feat1 = (const float*)d_in[0];
  const float* feat2 = (const float*)d_in[1];
  const float* Wq  = (const float*)d_in[2];
  const float* bq  = (const float*)d_in[3];
  const float* Wk  = (const float*)d_in[4];
  const float* bk  = (const float*)d_in[5];
  const float* Wv  = (const float*)d_in[6];
  const float* bv  = (const float*)d_in[7];
  const float* Wfc = (const float*)d_in[8];
  const float* bfc = (const float*)d_in[9];
  float* out = (float*)d_out;
  char* ws = (char*)d_ws;

  // workspace layout: 32.75 MB total (proven-safe footprint)
  short* Qw   = (short*)(ws);                       // 8 MB  [B][S1][F]
  short* Kw   = (short*)(ws + (size_t)(8u  << 20)); // 8 MB  [B][S2][F]
  short* Vtw  = (short*)(ws + (size_t)(16u << 20)); // 8 MB  [B][F][S2]
  short* AOw  = (short*)(ws + (size_t)(24u << 20)); // 8 MB  [B][S1][F]
  short* Wqt  = (short*)(ws + (size_t)(32u << 20)); // 256KB [F][D]
  short* Wkt  = Wqt + 256 * 512;
  short* Wvt  = Wkt + 256 * 512;
  short* Wfct = Wvt + 256 * 512;                    // [256][256]

  wtrans_kernel<<<dim3(32, 4), 256, 0, stream>>>(Wq, Wk, Wv, Wfc, Wqt, Wkt, Wvt, Wfct);
  proj_kernel<<<dim3(256, 3), 256, 0, stream>>>(feat1, feat2, Wqt, Wkt, Wvt,
                                                bq, bk, bv, Qw, Kw, Vtw);
  flash_kernel<<<dim3(256), 512, 0, stream>>>(Qw, Kw, Vtw, AOw);
  fc_kernel<<<dim3(256, 2), 256, 0, stream>>>(AOw, Wfct, bfc, out);
}

// Round 5
// 191.193 us; speedup vs baseline: 1.0508x; 1.0067x over previous
//
#include <hip/hip_runtime.h>
#include <hip/hip_bf16.h>

#define B_ 8
#define S1_ 2048
#define S2_ 2048
#define D_ 512
#define F_ 256

typedef __attribute__((ext_vector_type(4))) float f32x4;
typedef __attribute__((ext_vector_type(8))) short s16x8;
typedef __attribute__((ext_vector_type(4))) short s16x4;

__device__ __forceinline__ short f2bf(float x) {
  union { float f; unsigned u; } v; v.f = x;
  unsigned r = v.u + 0x7fffu + ((v.u >> 16) & 1u);
  return (short)(r >> 16);
}

__device__ __forceinline__ int pk2bf(float a, float b) {
  union { __hip_bfloat162 h; int i; } u;
  u.h = __float22bfloat162_rn(make_float2(a, b));
  return u.i;
}

// ---------------- weight transpose via LDS tile (coalesced both ways) ------
__global__ __launch_bounds__(256) void wtrans_kernel(
    const float* __restrict__ Wq, const float* __restrict__ Wk,
    const float* __restrict__ Wv, const float* __restrict__ Wfc,
    short* __restrict__ Wqt, short* __restrict__ Wkt,
    short* __restrict__ Wvt, short* __restrict__ Wfct) {
  int y = blockIdx.y;
  const float* W; short* Wt; int D;
  if (y == 0)      { W = Wq;  Wt = Wqt;  D = 512; }
  else if (y == 1) { W = Wk;  Wt = Wkt;  D = 512; }
  else if (y == 2) { W = Wv;  Wt = Wvt;  D = 512; }
  else             { W = Wfc; Wt = Wfct; D = 256; }
  int tiles_d = D >> 6;
  int bx = blockIdx.x;
  if (bx >= tiles_d * 4) return;
  int d0 = (bx % tiles_d) * 64, f0 = (bx / tiles_d) * 64;

  __shared__ short Ts[64][68];
  int t = threadIdx.x;
  int r = t >> 2, c16 = (t & 3) * 16;
  {
    const float* src = W + (size_t)(d0 + r) * F_ + f0 + c16;
    f32x4 v0 = *(const f32x4*)(src);
    f32x4 v1 = *(const f32x4*)(src + 4);
    f32x4 v2 = *(const f32x4*)(src + 8);
    f32x4 v3 = *(const f32x4*)(src + 12);
    s16x8 s0, s1;
    ((int*)&s0)[0] = pk2bf(v0[0], v0[1]); ((int*)&s0)[1] = pk2bf(v0[2], v0[3]);
    ((int*)&s0)[2] = pk2bf(v1[0], v1[1]); ((int*)&s0)[3] = pk2bf(v1[2], v1[3]);
    ((int*)&s1)[0] = pk2bf(v2[0], v2[1]); ((int*)&s1)[1] = pk2bf(v2[2], v2[3]);
    ((int*)&s1)[2] = pk2bf(v3[0], v3[1]); ((int*)&s1)[3] = pk2bf(v3[2], v3[3]);
    *(s16x8*)(&Ts[r][c16]) = s0;
    *(s16x8*)(&Ts[r][c16 + 8]) = s1;
  }
  __syncthreads();
  {
    int fr = t >> 2, dc16 = (t & 3) * 16;
    s16x8 o0, o1;
    for (int j = 0; j < 8; ++j) o0[j] = Ts[dc16 + j][fr];
    for (int j = 0; j < 8; ++j) o1[j] = Ts[dc16 + 8 + j][fr];
    short* dst = Wt + (size_t)(f0 + fr) * D + d0 + dc16;
    *(s16x8*)dst = o0;
    *(s16x8*)(dst + 8) = o1;
  }
}

// ---------------- QKV projection: R0 verbatim (proven fastest) ------------
__global__ __launch_bounds__(256, 3) void proj_kernel(
    const float* __restrict__ feat1, const float* __restrict__ feat2,
    const short* __restrict__ Wqt, const short* __restrict__ Wkt,
    const short* __restrict__ Wvt,
    const float* __restrict__ bq, const float* __restrict__ bk,
    const float* __restrict__ bv,
    short* __restrict__ Qw, short* __restrict__ Kw, short* __restrict__ Vtw) {
  const float* A; const short* Wt; const float* bias; short* outp;
  float scale; int trans;
  if (blockIdx.y == 0)      { A = feat1; Wt = Wqt; bias = bq; outp = Qw;  scale = 0.0625f; trans = 0; }
  else if (blockIdx.y == 1) { A = feat2; Wt = Wkt; bias = bk; outp = Kw;  scale = 1.0f;    trans = 0; }
  else                      { A = feat2; Wt = Wvt; bias = bv; outp = Vtw; scale = 1.0f;    trans = 1; }

  __shared__ __align__(16) short As[64][72];    // A tile 64x64 bf16
  __shared__ __align__(16) short Ws[256][72];   // W tile 256x64 bf16

  int m0 = blockIdx.x * 64;
  int t = threadIdx.x;
  int w = t >> 6, L = t & 63, rowA = L & 15, quad = L >> 4;
  int ar = t >> 2, ac16 = (t & 3) * 16;   // A staging: 4 lanes/row

  f32x4 acc[4][4];
  for (int i = 0; i < 4; ++i)
    for (int j = 0; j < 4; ++j) acc[i][j] = (f32x4){0.f, 0.f, 0.f, 0.f};

  for (int k0 = 0; k0 < D_; k0 += 64) {
    {   // stage A 64x64 fp32->bf16: each thread 16 floats
      const float* src = A + (size_t)(m0 + ar) * D_ + k0 + ac16;
      f32x4 v0 = *(const f32x4*)(src);
      f32x4 v1 = *(const f32x4*)(src + 4);
      f32x4 v2 = *(const f32x4*)(src + 8);
      f32x4 v3 = *(const f32x4*)(src + 12);
      s16x8 s0, s1;
      ((int*)&s0)[0] = pk2bf(v0[0], v0[1]); ((int*)&s0)[1] = pk2bf(v0[2], v0[3]);
      ((int*)&s0)[2] = pk2bf(v1[0], v1[1]); ((int*)&s0)[3] = pk2bf(v1[2], v1[3]);
      ((int*)&s1)[0] = pk2bf(v2[0], v2[1]); ((int*)&s1)[1] = pk2bf(v2[2], v2[3]);
      ((int*)&s1)[2] = pk2bf(v3[0], v3[1]); ((int*)&s1)[3] = pk2bf(v3[2], v3[3]);
      *(s16x8*)(&As[ar][ac16]) = s0;
      *(s16x8*)(&As[ar][ac16 + 8]) = s1;
    }
    for (int p = 0; p < 4; ++p) {   // stage W 256x64: 4 passes of 64 rows
      int r = (t >> 2) + p * 64;
      const short* src = Wt + (size_t)r * D_ + k0 + ac16;
      *(s16x8*)(&Ws[r][ac16]) = *(const s16x8*)(src);
      *(s16x8*)(&Ws[r][ac16 + 8]) = *(const s16x8*)(src + 8);
    }
    __syncthreads();
    for (int kt = 0; kt < 2; ++kt) {
      s16x8 a[4];
      for (int mt = 0; mt < 4; ++mt)
        a[mt] = *(const s16x8*)(&As[mt * 16 + rowA][kt * 32 + quad * 8]);
      for (int nt = 0; nt < 4; ++nt) {
        s16x8 bfr = *(const s16x8*)(&Ws[w * 64 + nt * 16 + rowA][kt * 32 + quad * 8]);
        for (int mt = 0; mt < 4; ++mt)
          acc[mt][nt] = __builtin_amdgcn_mfma_f32_16x16x32_bf16(a[mt], bfr, acc[mt][nt], 0, 0, 0);
      }
    }
    __syncthreads();
  }

  if (!trans) {
    float bn[4];
    for (int nt = 0; nt < 4; ++nt) bn[nt] = bias[w * 64 + nt * 16 + rowA];
    for (int mt = 0; mt < 4; ++mt) {
      int m = m0 + mt * 16 + quad * 4;
      for (int nt = 0; nt < 4; ++nt) {
        int n = w * 64 + nt * 16 + rowA;
        for (int r = 0; r < 4; ++r)
          outp[(size_t)(m + r) * F_ + n] = f2bf((acc[mt][nt][r] + bn[nt]) * scale);
      }
    }
  } else {
    int bb = m0 >> 11;
    int tbase = m0 & (S2_ - 1);
    float bn[4];
    for (int nt = 0; nt < 4; ++nt) bn[nt] = bias[w * 64 + nt * 16 + rowA];
    for (int nt = 0; nt < 4; ++nt) {
      int f = w * 64 + nt * 16 + rowA;
      for (int mt = 0; mt < 4; ++mt) {
        int tt = tbase + mt * 16 + quad * 4;
        s16x4 o;
        for (int r = 0; r < 4; ++r) o[r] = f2bf(acc[mt][nt][r] + bn[nt]);
        *(s16x4*)(outp + ((size_t)bb * F_ + f) * S2_ + tt) = o;
      }
    }
  }
}

// ---------------- flash attention: R0 loop, SINGLE CHANGE = XOR swizzle ----
// Ks/Vs unpadded with 16B-chunk XOR swizzle (chunk ^= row&7) applied on BOTH
// the reg-staged ds_write and every ds_read. No global_load_lds (no vmcnt
// drain mechanism). Targets SQ_LDS_BANK_CONFLICT 4.7M -> <2M. Ps unchanged.
__global__ __launch_bounds__(512, 2) void flash_kernel(
    const short* __restrict__ Q,    // [B][S1][F] bf16 (scaled)
    const short* __restrict__ K,    // [B][S2][F] bf16
    const short* __restrict__ Vt,   // [B][F][S2] bf16
    short* __restrict__ O) {        // [B][S1][F] bf16 (normalized)
  __shared__ __align__(16) short Ks[2][64 * 256];  // 65536 B (swizzled)
  __shared__ __align__(16) short Vs[2][256 * 64];  // 65536 B (swizzled)
  __shared__ __align__(16) short Ps[2][64][72];    // 18432 B (sum 149504)

  int b = blockIdx.x & 7;            // XCD-aware: batch = block % 8
  int s0 = (blockIdx.x >> 3) * 64;
  int t = threadIdx.x;
  int w = t >> 6, L = t & 63, rowA = L & 15, quad = L >> 4;
  int isS = (w < 4);

  const short* Kb = K + (size_t)b * S2_ * F_;
  const short* Vb = Vt + (size_t)b * F_ * S2_;

  int kr = t >> 5, kc = t & 31;      // K staging: row, 16B-chunk
  int vr = t >> 3, vc = t & 7;       // V staging: row, 16B-chunk
  int kcs = (kc ^ (kr & 7)) * 8;     // swizzled chunk (shorts); row&7==kr&7
  int vcs = (vc ^ (vr & 7)) * 8;     // swizzled chunk (shorts); row&7==vr&7
  int rx = rowA & 7;                 // read-side XOR key (row&7 == rowA&7)

  int rs = (w & 1) * 32, cs = ((w >> 1) & 1) * 32;   // S-wave quadrant
  int mg = (w - 4) & 1, fg = ((w - 4) >> 1) & 1;     // PV-wave tile

  s16x8 qf[2][8];
  if (isS) {
    const short* Qb = Q + ((size_t)b * S1_ + s0 + rs) * F_;
    for (int mt = 0; mt < 2; ++mt)
      for (int kt = 0; kt < 8; ++kt)
        qf[mt][kt] = *(const s16x8*)(Qb + (size_t)(mt * 16 + rowA) * F_ + kt * 32 + quad * 8);
  }
  f32x4 o[2][8];
  for (int i = 0; i < 2; ++i)
    for (int j = 0; j < 8; ++j) o[i][j] = (f32x4){0.f, 0.f, 0.f, 0.f};
  float l_lane[2][4] = {{0.f,0.f,0.f,0.f},{0.f,0.f,0.f,0.f}};

  s16x8 kpre[4], vpre[4];
  for (int p = 0; p < 4; ++p)
    kpre[p] = *(const s16x8*)(Kb + (size_t)(kr + p * 16) * F_ + kc * 8);
  for (int p = 0; p < 4; ++p)
    *(s16x8*)(&Ks[0][(kr + p * 16) * 256 + kcs]) = kpre[p];
  for (int p = 0; p < 4; ++p)
    kpre[p] = *(const s16x8*)(Kb + (size_t)(64 + kr + p * 16) * F_ + kc * 8);
  for (int p = 0; p < 4; ++p)
    vpre[p] = *(const s16x8*)(Vb + (size_t)(vr + p * 64) * S2_ + vc * 8);

  for (int it = 0; it <= 32; ++it) {
    int cb = it & 1;
    __syncthreads();
    if (it < 32) {
      for (int p = 0; p < 4; ++p)
        *(s16x8*)(&Vs[cb][(vr + p * 64) * 64 + vcs]) = vpre[p];
      if (it < 31) {
        for (int p = 0; p < 4; ++p)
          *(s16x8*)(&Ks[1 - cb][(kr + p * 16) * 256 + kcs]) = kpre[p];
        int n0 = (it + 1) * 64;
        for (int p = 0; p < 4; ++p)
          vpre[p] = *(const s16x8*)(Vb + (size_t)(vr + p * 64) * S2_ + n0 + vc * 8);
      }
      if (it < 30) {
        int n0 = (it + 2) * 64;
        for (int p = 0; p < 4; ++p)
          kpre[p] = *(const s16x8*)(Kb + (size_t)(n0 + kr + p * 16) * F_ + kc * 8);
      }
    }
    if (isS) {
      if (it < 32) {
        f32x4 s[2][2];
        for (int i = 0; i < 2; ++i)
          for (int j = 0; j < 2; ++j) s[i][j] = (f32x4){0.f, 0.f, 0.f, 0.f};
        for (int kt = 0; kt < 8; ++kt) {
          int cj = ((kt * 4 + quad) ^ rx) * 8;   // swizzled chunk offset
          s16x8 bf0 = *(const s16x8*)(&Ks[cb][(cs + rowA) * 256 + cj]);
          s16x8 bf1 = *(const s16x8*)(&Ks[cb][(cs + 16 + rowA) * 256 + cj]);
          for (int mt = 0; mt < 2; ++mt) {
            s[mt][0] = __builtin_amdgcn_mfma_f32_16x16x32_bf16(qf[mt][kt], bf0, s[mt][0], 0, 0, 0);
            s[mt][1] = __builtin_amdgcn_mfma_f32_16x16x32_bf16(qf[mt][kt], bf1, s[mt][1], 0, 0, 0);
          }
        }
        for (int mt = 0; mt < 2; ++mt)
          for (int nt = 0; nt < 2; ++nt)
            for (int r = 0; r < 4; ++r) {
              float p = __expf(s[mt][nt][r]);
              l_lane[mt][r] += p;
              Ps[cb][rs + mt * 16 + quad * 4 + r][cs + nt * 16 + rowA] = f2bf(p);
            }
      }
    } else {
      if (it > 0) {
        int pb = 1 - cb;
        s16x8 pa[2][2];
        for (int mt = 0; mt < 2; ++mt)
          for (int kt = 0; kt < 2; ++kt)
            pa[mt][kt] = *(const s16x8*)(&Ps[pb][mg * 32 + mt * 16 + rowA][kt * 32 + quad * 8]);
        for (int ft = 0; ft < 8; ++ft)
          for (int kt = 0; kt < 2; ++kt) {
            int cj = ((kt * 4 + quad) ^ rx) * 8;   // swizzled chunk offset
            s16x8 vf = *(const s16x8*)(&Vs[pb][(fg * 128 + ft * 16 + rowA) * 64 + cj]);
            for (int mt = 0; mt < 2; ++mt)
              o[mt][ft] = __builtin_amdgcn_mfma_f32_16x16x32_bf16(pa[mt][kt], vf, o[mt][ft], 0, 0, 0);
          }
      }
    }
  }

  float* lf = (float*)&Ks[0][0];   // [2 col-halves][64 rows]
  if (isS) {
    for (int mt = 0; mt < 2; ++mt)
      for (int r = 0; r < 4; ++r) {
        float x = l_lane[mt][r];
        for (int off = 1; off < 16; off <<= 1)
          x += __shfl_xor(x, off, 64);
        if (rowA == 0)
          lf[((w >> 1) & 1) * 64 + rs + mt * 16 + quad * 4 + r] = x;
      }
  }
  __syncthreads();
  if (!isS) {
    short* Ob = O + ((size_t)b * S1_ + s0) * F_;
    for (int mt = 0; mt < 2; ++mt)
      for (int r = 0; r < 4; ++r) {
        int row = mg * 32 + mt * 16 + quad * 4 + r;
        float inv = 1.0f / (lf[row] + lf[64 + row]);
        for (int ft = 0; ft < 8; ++ft)
          Ob[(size_t)row * F_ + fg * 128 + ft * 16 + rowA] = f2bf(o[mt][ft][r] * inv);
      }
  }
}

// ---------------- FC: 64x128 tile, 512 blocks (2/CU), prefetched ----------
__global__ __launch_bounds__(256) void fc_kernel(
    const short* __restrict__ AO,   // [16384][256] bf16
    const short* __restrict__ Wt,   // [256 g][256 k] bf16
    const float* __restrict__ bias,
    float* __restrict__ out) {
  __shared__ __align__(16) short As[64][72];    // 9216 B
  __shared__ __align__(16) short Ws[128][72];   // 18432 B (27.6 KB total)

  int m0 = blockIdx.x * 64;
  int n0 = blockIdx.y * 128;
  int t = threadIdx.x;
  int w = t >> 6, L = t & 63, rowA = L & 15, quad = L >> 4;
  int wy = w & 1, wx = w >> 1;   // 32-row half, 64-col half

  int ar = t >> 2, ac16 = (t & 3) * 16;   // A staging: 16 shorts/thread
  int wr = t >> 1, wc32 = (t & 1) * 32;   // W staging: 32 shorts/thread

  s16x8 apre[2], wpre[4];
  {   // prologue k0 = 0
    const short* asrc = AO + (size_t)(m0 + ar) * F_ + ac16;
    apre[0] = *(const s16x8*)(asrc);
    apre[1] = *(const s16x8*)(asrc + 8);
    const short* wsrc = Wt + (size_t)(n0 + wr) * F_ + wc32;
    for (int j = 0; j < 4; ++j) wpre[j] = *(const s16x8*)(wsrc + j * 8);
  }

  f32x4 acc[2][4];
  for (int i = 0; i < 2; ++i)
    for (int j = 0; j < 4; ++j) acc[i][j] = (f32x4){0.f, 0.f, 0.f, 0.f};

  for (int k0 = 0; k0 < F_; k0 += 64) {
    *(s16x8*)(&As[ar][ac16]) = apre[0];
    *(s16x8*)(&As[ar][ac16 + 8]) = apre[1];
    for (int j = 0; j < 4; ++j) *(s16x8*)(&Ws[wr][wc32 + j * 8]) = wpre[j];
    __syncthreads();
    if (k0 + 64 < F_) {   // prefetch next slab
      const short* asrc = AO + (size_t)(m0 + ar) * F_ + k0 + 64 + ac16;
      apre[0] = *(const s16x8*)(asrc);
      apre[1] = *(const s16x8*)(asrc + 8);
      const short* wsrc = Wt + (size_t)(n0 + wr) * F_ + k0 + 64 + wc32;
      for (int j = 0; j < 4; ++j) wpre[j] = *(const s16x8*)(wsrc + j * 8);
    }
    for (int kt = 0; kt < 2; ++kt) {
      s16x8 a[2];
      for (int mt = 0; mt < 2; ++mt)
        a[mt] = *(const s16x8*)(&As[wy * 32 + mt * 16 + rowA][kt * 32 + quad * 8]);
      for (int nt = 0; nt < 4; ++nt) {
        s16x8 bfr = *(const s16x8*)(&Ws[wx * 64 + nt * 16 + rowA][kt * 32 + quad * 8]);
        for (int mt = 0; mt < 2; ++mt)
          acc[mt][nt] = __builtin_amdgcn_mfma_f32_16x16x32_bf16(a[mt], bfr, acc[mt][nt], 0, 0, 0);
      }
    }
    __syncthreads();
  }

  float bn[4];
  for (int nt = 0; nt < 4; ++nt) bn[nt] = bias[n0 + wx * 64 + nt * 16 + rowA];
  for (int mt = 0; mt < 2; ++mt) {
    int m = m0 + wy * 32 + mt * 16 + quad * 4;
    for (int nt = 0; nt < 4; ++nt) {
      int n = n0 + wx * 64 + nt * 16 + rowA;
      for (int r = 0; r < 4; ++r)
        out[(size_t)(m + r) * F_ + n] = acc[mt][nt][r] + bn[nt];
    }
  }
}

extern "C" void kernel_launch(void* const* d_in, const int* in_sizes, int n_in,
                              void* d_out, int out_size, void* d_ws, size_t ws_size,
                              hipStream_t stream) {
  const float* feat1 = (const float*)d_in[0];
  const float* feat2 = (const float*)d_in[1];
  const float* Wq  = (const float*)d_in[2];
  const float* bq  = (const float*)d_in[3];
  const float* Wk  = (const float*)d_in[4];
  const float* bk  = (const float*)d_in[5];
  const float* Wv  = (const float*)d_in[6];
  const float* bv  = (const float*)d_in[7];
  const float* Wfc = (const float*)d_in[8];
  const float* bfc = (const float*)d_in[9];
  float* out = (float*)d_out;
  char* ws = (char*)d_ws;

  // workspace layout: 32.75 MB total (proven-safe footprint)
  short* Qw   = (short*)(ws);                       // 8 MB  [B][S1][F]
  short* Kw   = (short*)(ws + (size_t)(8u  << 20)); // 8 MB  [B][S2][F]
  short* Vtw  = (short*)(ws + (size_t)(16u << 20)); // 8 MB  [B][F][S2]
  short* AOw  = (short*)(ws + (size_t)(24u << 20)); // 8 MB  [B][S1][F]
  short* Wqt  = (short*)(ws + (size_t)(32u << 20)); // 256KB [F][D]
  short* Wkt  = Wqt + 256 * 512;
  short* Wvt  = Wkt + 256 * 512;
  short* Wfct = Wvt + 256 * 512;                    // [256][256]

  wtrans_kernel<<<dim3(32, 4), 256, 0, stream>>>(Wq, Wk, Wv, Wfc, Wqt, Wkt, Wvt, Wfct);
  proj_kernel<<<dim3(256, 3), 256, 0, stream>>>(feat1, feat2, Wqt, Wkt, Wvt,
                                                bq, bk, bv, Qw, Kw, Vtw);
  flash_kernel<<<dim3(256), 512, 0, stream>>>(Qw, Kw, Vtw, AOw);
  fc_kernel<<<dim3(256, 2), 256, 0, stream>>>(AOw, Wfct, bfc, out);
}